// Round 1
// baseline (588.957 us; speedup 1.0000x reference)
//
#include <hip/hip_runtime.h>
#include <math.h>

#define B_SZ 256
#define N_SZ 200
#define NN (N_SZ * N_SZ)          // 40000
#define FIN 200
#define OUT_F 256
#define NCLS 8
#define KSEL 3980
#define NUPPER 20100              // N*(N+1)/2
#define SYM_STRIDE 20128

#define EMB_OFF (B_SZ * N_SZ * NCLS)               // 409600
#define ADJ_OFF (EMB_OFF + B_SZ * N_SZ * OUT_F)    // 13516800

__device__ __forceinline__ unsigned sortkey(float f) {
    unsigned u = __float_as_uint(f);
    return (u & 0x80000000u) ? ~u : (u | 0x80000000u);
}

// -------- K1: sym + radix-select top-K + write 0/1 adj ----------------------
__global__ __launch_bounds__(256) void k1_sym_select(
    const float* __restrict__ gu, const float* __restrict__ nets,
    const int* __restrict__ net_index, float* __restrict__ symUp,
    float* __restrict__ out_base)
{
    const int b = blockIdx.x;
    const int tid = threadIdx.x;
    const float* ub = gu + (size_t)b * NN;
    const float* lg = nets + (size_t)net_index[b] * NN;
    float* sb = symUp + (size_t)b * SYM_STRIDE;
    float* adj = out_base + ADJ_OFF + (size_t)b * NN;

    // phase 0: zero adj
    for (int t = tid; t < NN; t += 256) adj[t] = 0.0f;

    // phase 1: sym upper triangle (incl diag), row-packed
    int base = 0;  // T(i) = running start of row i
    for (int i = 0; i < N_SZ; ++i) {
        for (int j = i + tid; j < N_SZ; j += 256) {
            float uij = ub[i * N_SZ + j];
            float uji = ub[j * N_SZ + i];
            uij = fminf(fmaxf(uij, 1e-10f), 1.0f - 1e-10f);
            uji = fminf(fmaxf(uji, 1e-10f), 1.0f - 1e-10f);
            float gij = -logf(-logf(uij));
            float gji = -logf(-logf(uji));
            float s = 0.5f * ((lg[i * N_SZ + j] + gij) + (lg[j * N_SZ + i] + gji));
            sb[base + (j - i)] = s;
        }
        base += N_SZ - i;
    }
    __syncthreads();

    // phase 2: MSB-first radix select (k-th largest of NUPPER keys)
    __shared__ unsigned hist[256];
    __shared__ unsigned sPrefix;
    __shared__ int sKK;
    unsigned prefix = 0;
    int kk = KSEL;
    for (int round = 0; round < 4; ++round) {
        const int shift = 24 - 8 * round;
        hist[tid] = 0;
        __syncthreads();
        for (int idx = tid; idx < NUPPER; idx += 256) {
            unsigned key = sortkey(sb[idx]);
            bool in = (round == 0) || ((key >> (shift + 8)) == prefix);
            if (in) atomicAdd(&hist[(key >> shift) & 255u], 1u);
        }
        __syncthreads();
        if (tid == 0) {
            int cum = 0; unsigned bsel = 0; int nkk = kk;
            for (int bn = 255; bn >= 0; --bn) {
                int c = (int)hist[bn];
                if (cum + c >= kk) { bsel = (unsigned)bn; nkk = kk - cum; break; }
                cum += c;
            }
            sPrefix = (prefix << 8) | bsel;
            sKK = nkk;
        }
        __syncthreads();
        prefix = sPrefix;
        kk = sKK;
        __syncthreads();
    }
    const unsigned kthKey = prefix;   // exact key of k-th largest
    // kk = number of elements equal to kthKey to include (ties by lowest flat idx)

    // phase 3: write selected edges (symmetrized; diag handled naturally)
    __shared__ int eqList[256];
    __shared__ int eqCnt;
    if (tid == 0) eqCnt = 0;
    __syncthreads();
    base = 0;
    for (int i = 0; i < N_SZ; ++i) {
        for (int j = i + tid; j < N_SZ; j += 256) {
            unsigned key = sortkey(sb[base + (j - i)]);
            if (key > kthKey) {
                adj[i * N_SZ + j] = 1.0f;
                adj[j * N_SZ + i] = 1.0f;
            } else if (key == kthKey) {
                int p = atomicAdd(&eqCnt, 1);
                if (p < 256) eqList[p] = i * N_SZ + j;
            }
        }
        base += N_SZ - i;
    }
    __syncthreads();
    if (tid == 0) {
        int e = eqCnt < 256 ? eqCnt : 256;
        // sort ascending by flat index (tiny list)
        for (int a = 1; a < e; ++a) {
            int v = eqList[a]; int c = a - 1;
            while (c >= 0 && eqList[c] > v) { eqList[c + 1] = eqList[c]; --c; }
            eqList[c + 1] = v;
        }
        int take = kk < e ? kk : e;
        for (int t = 0; t < take; ++t) {
            int fi = eqList[t];
            int i = fi / N_SZ, j = fi % N_SZ;
            adj[i * N_SZ + j] = 1.0f;
            adj[j * N_SZ + i] = 1.0f;
        }
    }
}

// -------- K2: XW = x @ w_gnn  ([51200 x 200] @ [200 x 256]) -----------------
__global__ __launch_bounds__(256) void k2_xw(
    const float* __restrict__ x, const float* __restrict__ wg,
    float* __restrict__ xw)
{
    __shared__ float xs[64][FIN];
    const int tid = threadIdx.x;
    const int r0 = blockIdx.x * 64;
    for (int t = tid; t < 64 * FIN; t += 256) {
        int r = t / FIN, c = t % FIN;
        xs[r][c] = x[(size_t)(r0 + r) * FIN + c];
    }
    __syncthreads();
    const int g = tid >> 6;
    const int lane = tid & 63;
    float acc[16][4];
    #pragma unroll
    for (int r = 0; r < 16; ++r)
        #pragma unroll
        for (int c = 0; c < 4; ++c) acc[r][c] = 0.0f;

    for (int k = 0; k < FIN; ++k) {
        float wv0 = wg[k * OUT_F + lane];
        float wv1 = wg[k * OUT_F + lane + 64];
        float wv2 = wg[k * OUT_F + lane + 128];
        float wv3 = wg[k * OUT_F + lane + 192];
        #pragma unroll
        for (int r = 0; r < 16; ++r) {
            float xv = xs[g * 16 + r][k];
            acc[r][0] += xv * wv0;
            acc[r][1] += xv * wv1;
            acc[r][2] += xv * wv2;
            acc[r][3] += xv * wv3;
        }
    }
    #pragma unroll
    for (int r = 0; r < 16; ++r) {
        size_t row = (size_t)(r0 + g * 16 + r);
        xw[row * OUT_F + lane]        = acc[r][0];
        xw[row * OUT_F + lane + 64]   = acc[r][1];
        xw[row * OUT_F + lane + 128]  = acc[r][2];
        xw[row * OUT_F + lane + 192]  = acc[r][3];
    }
}

// -------- K3: emb = relu(adj @ XW); out = emb @ w_lin + b -------------------
__global__ __launch_bounds__(256) void k3_emb_out(
    const float* __restrict__ xw, const float* __restrict__ wl,
    const float* __restrict__ bl, float* __restrict__ out_base)
{
    // XCD-aware swizzle: keep all rows of a batch on one XCD so XW[b] stays L2-hot
    unsigned h = blockIdx.x;
    unsigned xcd = h & 7u;
    unsigned q = h >> 3;                 // 0..6399
    unsigned b = xcd * 32u + q / N_SZ;
    unsigned i = q % N_SZ;

    const int tid = threadIdx.x;
    const float* adj = out_base + ADJ_OFF + (size_t)b * NN + (size_t)i * N_SZ;

    __shared__ unsigned long long masks[4];
    __shared__ float red[4][NCLS];

    bool sel = false;
    if (tid < N_SZ) sel = (adj[tid] != 0.0f);
    unsigned long long m = __ballot(sel);
    const int wave = tid >> 6;
    const int lane = tid & 63;
    if (lane == 0) masks[wave] = m;
    __syncthreads();

    float acc = 0.0f;
    const float* xwb = xw + (size_t)b * N_SZ * OUT_F;
    #pragma unroll 1
    for (int w = 0; w < 4; ++w) {
        unsigned long long mm = masks[w];
        while (mm) {
            int bit = __builtin_ctzll(mm);
            int jj = w * 64 + bit;
            acc += xwb[(size_t)jj * OUT_F + tid];
            mm &= mm - 1;
        }
    }
    float emb = fmaxf(acc, 0.0f);
    out_base[EMB_OFF + ((size_t)b * N_SZ + i) * OUT_F + tid] = emb;

    float p[NCLS];
    #pragma unroll
    for (int c = 0; c < NCLS; ++c) p[c] = emb * wl[tid * NCLS + c];
    #pragma unroll
    for (int c = 0; c < NCLS; ++c) {
        #pragma unroll
        for (int off = 32; off >= 1; off >>= 1)
            p[c] += __shfl_xor(p[c], off, 64);
    }
    if (lane == 0) {
        #pragma unroll
        for (int c = 0; c < NCLS; ++c) red[wave][c] = p[c];
    }
    __syncthreads();
    if (tid < NCLS) {
        float s = red[0][tid] + red[1][tid] + red[2][tid] + red[3][tid] + bl[tid];
        out_base[((size_t)b * N_SZ + i) * NCLS + tid] = s;
    }
}

extern "C" void kernel_launch(void* const* d_in, const int* in_sizes, int n_in,
                              void* d_out, int out_size, void* d_ws, size_t ws_size,
                              hipStream_t stream) {
    const float* x    = (const float*)d_in[0];
    const float* gu   = (const float*)d_in[1];
    const float* nets = (const float*)d_in[2];
    const float* wg   = (const float*)d_in[3];
    const float* wl   = (const float*)d_in[4];
    const float* bl   = (const float*)d_in[5];
    const int*   nidx = (const int*)d_in[6];
    float* out = (float*)d_out;

    // ws: symUp (20.6 MB, K1 only) overlapped with XW (52.4 MB, K2/K3) —
    // K1 completes before K2 writes, same stream.
    float* symUp = (float*)d_ws;
    float* xw    = (float*)d_ws;

    k1_sym_select<<<B_SZ, 256, 0, stream>>>(gu, nets, nidx, symUp, out);
    k2_xw<<<(B_SZ * N_SZ) / 64, 256, 0, stream>>>(x, wg, xw);
    k3_emb_out<<<B_SZ * N_SZ, 256, 0, stream>>>(xw, wl, bl, out);
}

// Round 2
// 438.762 us; speedup vs baseline: 1.3423x; 1.3423x over previous
//
#include <hip/hip_runtime.h>
#include <math.h>

#define B_SZ 256
#define N_SZ 200
#define NN (N_SZ * N_SZ)          // 40000
#define FIN 200
#define OUT_F 256
#define NCLS 8
#define KSEL 3980
#define NUPPER 20100              // N*(N+1)/2
#define KSTRIDE 20128
#define NT 7                      // ceil(200/32) tiles per dim
#define NTILES 28                 // NT*(NT+1)/2 upper tile pairs
#define SCAN_CH 16
#define CAND_CAP 2048

#define EMB_OFF (B_SZ * N_SZ * NCLS)               // 409600
#define ADJ_OFF (EMB_OFF + B_SZ * N_SZ * OUT_F)    // 13516800

// ---- ws layout (bytes) ----
// keys:    [0, 20,611,072)                  B * KSTRIDE * 4
// hist:    [20,611,072, +1,048,576)         4 rounds * B * 256 * 4
// sel:     [21,659,648, +2,048)             B * 2 u32
// candCnt: [21,661,696, +1,024)             B u32
// cand:    [21,662,720, +2,097,152)         B * CAND_CAP u32
// XW aliases [0, 52.4MB) -- written by K2 strictly after K1 chain done.
#define KEYS_OFF_B   0
#define HIST_OFF_B   20611072
#define SEL_OFF_B    21659648
#define CCNT_OFF_B   21661696
#define CAND_OFF_B   21662720
#define MEMSET_LEN   (1048576 + 2048 + 1024)

__device__ __forceinline__ unsigned sortkey(float f) {
    unsigned u = __float_as_uint(f);
    return (u & 0x80000000u) ? ~u : (u | 0x80000000u);
}

__device__ __forceinline__ void tile_decode(int t, int& ti, int& tj) {
    int a = 0, rem = t;
    while (rem >= NT - a) { rem -= NT - a; ++a; }
    ti = a; tj = a + rem;
}

// -------- kA: compute sym keys (packed upper-tri) + round-0 histogram -------
__global__ __launch_bounds__(256) void kA(
    const float* __restrict__ gu, const float* __restrict__ nets,
    const int* __restrict__ net_index, unsigned* __restrict__ keys,
    unsigned* __restrict__ hist0)
{
    const int blk = blockIdx.x;
    const int b = blk / NTILES;
    int ti, tj; tile_decode(blk % NTILES, ti, tj);
    const int i0 = ti * 32, j0 = tj * 32;
    const float* ub = gu + (size_t)b * NN;
    const float* lb = nets + (size_t)net_index[b] * NN;

    __shared__ float Hij[32][33];
    __shared__ float Hji[32][33];
    __shared__ unsigned hist[256];
    hist[threadIdx.x] = 0;

    const int r = threadIdx.x >> 5;
    const int c = threadIdx.x & 31;

    #pragma unroll
    for (int s = 0; s < 4; ++s) {
        int rr = r + 8 * s;
        int i = i0 + rr, j = j0 + c;
        if (i < N_SZ && j < N_SZ) {
            float u = ub[i * N_SZ + j];
            u = fminf(fmaxf(u, 1e-10f), 1.0f - 1e-10f);
            Hij[rr][c] = lb[i * N_SZ + j] - logf(-logf(u));
        }
        if (ti != tj) {
            int i2 = j0 + rr, j2 = i0 + c;
            if (i2 < N_SZ && j2 < N_SZ) {
                float u = ub[i2 * N_SZ + j2];
                u = fminf(fmaxf(u, 1e-10f), 1.0f - 1e-10f);
                Hji[rr][c] = lb[i2 * N_SZ + j2] - logf(-logf(u));
            }
        }
    }
    __syncthreads();

    unsigned* kb = keys + (size_t)b * KSTRIDE;
    #pragma unroll
    for (int s = 0; s < 4; ++s) {
        int rr = r + 8 * s;
        int i = i0 + rr, j = j0 + c;
        if (i < N_SZ && j < N_SZ && i <= j) {
            float hji = (ti == tj) ? Hij[c][rr] : Hji[c][rr];
            float sv = 0.5f * (Hij[rr][c] + hji);
            unsigned key = sortkey(sv);
            int base = i * N_SZ - (i * (i - 1)) / 2;
            kb[base + (j - i)] = key;
            atomicAdd(&hist[key >> 24], 1u);
        }
    }
    __syncthreads();
    if (hist[threadIdx.x]) atomicAdd(&hist0[b * 256 + threadIdx.x], hist[threadIdx.x]);
}

// -------- kSel: pick bucket for this round, update (prefix, kk) -------------
__global__ __launch_bounds__(256) void kSel(
    const unsigned* __restrict__ histr, unsigned* __restrict__ sel, int round)
{
    const int b = blockIdx.x;
    __shared__ unsigned h[256];
    h[threadIdx.x] = histr[b * 256 + threadIdx.x];
    __syncthreads();
    if (threadIdx.x == 0) {
        int kk = (round == 0) ? KSEL : (int)sel[b * 2 + 1];
        unsigned prefix = (round == 0) ? 0u : sel[b * 2];
        int cum = 0; int bsel = 0;
        for (int bn = 255; bn >= 0; --bn) {
            int cc = (int)h[bn];
            if (cum + cc >= kk) { bsel = bn; kk = kk - cum; break; }
            cum += cc;
        }
        sel[b * 2] = (prefix << 8) | (unsigned)bsel;
        sel[b * 2 + 1] = (unsigned)kk;
    }
}

// -------- kScan: histogram next byte among keys matching current prefix -----
__global__ __launch_bounds__(256) void kScan(
    const unsigned* __restrict__ keys, const unsigned* __restrict__ sel,
    unsigned* __restrict__ histr, int shift)
{
    const int blk = blockIdx.x;
    const int b = blk / SCAN_CH;
    const int ch = blk % SCAN_CH;
    const unsigned prefix = sel[b * 2];
    __shared__ unsigned hist[256];
    hist[threadIdx.x] = 0;
    __syncthreads();
    const unsigned* kb = keys + (size_t)b * KSTRIDE;
    const int per = (NUPPER + SCAN_CH - 1) / SCAN_CH;
    const int lo = ch * per;
    const int hi = (lo + per < NUPPER) ? lo + per : NUPPER;
    for (int idx = lo + threadIdx.x; idx < hi; idx += 256) {
        unsigned key = kb[idx];
        if ((key >> (shift + 8)) == prefix)
            atomicAdd(&hist[(key >> shift) & 255u], 1u);
    }
    __syncthreads();
    if (hist[threadIdx.x]) atomicAdd(&histr[b * 256 + threadIdx.x], hist[threadIdx.x]);
}

// -------- kW: write full 0/1 adj (both triangles), collect exact ties -------
__global__ __launch_bounds__(256) void kW(
    const unsigned* __restrict__ keys, const unsigned* __restrict__ sel,
    unsigned* __restrict__ candCnt, unsigned* __restrict__ cand,
    float* __restrict__ out_base)
{
    const int blk = blockIdx.x;
    const int b = blk / NTILES;
    int ti, tj; tile_decode(blk % NTILES, ti, tj);
    const int i0 = ti * 32, j0 = tj * 32;
    const unsigned kth = sel[b * 2];
    const unsigned* kb = keys + (size_t)b * KSTRIDE;
    float* adj = out_base + ADJ_OFF + (size_t)b * NN;

    __shared__ float V[32][33];
    const int r = threadIdx.x >> 5;
    const int c = threadIdx.x & 31;

    #pragma unroll
    for (int s = 0; s < 4; ++s) {
        int rr = r + 8 * s;
        int i = i0 + rr, j = j0 + c;
        if (i < N_SZ && j < N_SZ && i <= j) {
            int base = i * N_SZ - (i * (i - 1)) / 2;
            unsigned key = kb[base + (j - i)];
            float v = (key > kth) ? 1.0f : 0.0f;
            if (key == kth) {
                unsigned p = atomicAdd(&candCnt[b], 1u);
                if (p < CAND_CAP) cand[(size_t)b * CAND_CAP + p] = (unsigned)(i * N_SZ + j);
            }
            V[rr][c] = v;
            if (ti == tj) V[c][rr] = v;
        }
    }
    __syncthreads();
    #pragma unroll
    for (int s = 0; s < 4; ++s) {
        int rr = r + 8 * s;
        int i = i0 + rr, j = j0 + c;
        if (i < N_SZ && j < N_SZ) adj[i * N_SZ + j] = V[rr][c];
    }
    if (ti != tj) {
        #pragma unroll
        for (int s = 0; s < 4; ++s) {
            int rr = r + 8 * s;
            int i2 = j0 + rr, j2 = i0 + c;
            if (i2 < N_SZ && j2 < N_SZ) adj[i2 * N_SZ + j2] = V[c][rr];
        }
    }
}

// -------- kT: deterministically include first-kk ties by flat index ---------
__global__ void kT(const unsigned* __restrict__ sel,
                   const unsigned* __restrict__ candCnt,
                   const unsigned* __restrict__ cand,
                   float* __restrict__ out_base)
{
    const int b = blockIdx.x;
    if (threadIdx.x != 0) return;
    int kk = (int)sel[b * 2 + 1];
    int cnt = (int)candCnt[b];
    if (cnt > CAND_CAP) cnt = CAND_CAP;
    unsigned loc[64];  // realistic tie counts are tiny; take first kk by index
    // selection: repeatedly take min index
    float* adj = out_base + ADJ_OFF + (size_t)b * NN;
    int take = kk < cnt ? kk : cnt;
    // simple selection without full sort: take 'take' smallest indices
    unsigned used[64];
    int nu = 0;
    for (int t = 0; t < take; ++t) {
        unsigned best = 0xFFFFFFFFu;
        for (int q = 0; q < cnt; ++q) {
            unsigned v = cand[(size_t)b * CAND_CAP + q];
            bool skip = false;
            for (int u = 0; u < nu; ++u) if (used[u] == v) { skip = true; break; }
            if (!skip && v < best) best = v;
        }
        if (best == 0xFFFFFFFFu) break;
        if (nu < 64) used[nu++] = best;
        int i = (int)(best / N_SZ), j = (int)(best % N_SZ);
        adj[i * N_SZ + j] = 1.0f;
        adj[j * N_SZ + i] = 1.0f;
        (void)loc;
    }
}

// -------- K2: XW = x @ w_gnn  ([51200 x 200] @ [200 x 256]) -----------------
__global__ __launch_bounds__(256) void k2_xw(
    const float* __restrict__ x, const float* __restrict__ wg,
    float* __restrict__ xw)
{
    __shared__ float xs[64][FIN];
    const int tid = threadIdx.x;
    const int r0 = blockIdx.x * 64;
    for (int t = tid; t < 64 * FIN; t += 256) {
        int r = t / FIN, c = t % FIN;
        xs[r][c] = x[(size_t)(r0 + r) * FIN + c];
    }
    __syncthreads();
    const int g = tid >> 6;
    const int lane = tid & 63;
    float acc[16][4];
    #pragma unroll
    for (int r = 0; r < 16; ++r)
        #pragma unroll
        for (int c = 0; c < 4; ++c) acc[r][c] = 0.0f;

    for (int k = 0; k < FIN; ++k) {
        float wv0 = wg[k * OUT_F + lane];
        float wv1 = wg[k * OUT_F + lane + 64];
        float wv2 = wg[k * OUT_F + lane + 128];
        float wv3 = wg[k * OUT_F + lane + 192];
        #pragma unroll
        for (int r = 0; r < 16; ++r) {
            float xv = xs[g * 16 + r][k];
            acc[r][0] += xv * wv0;
            acc[r][1] += xv * wv1;
            acc[r][2] += xv * wv2;
            acc[r][3] += xv * wv3;
        }
    }
    #pragma unroll
    for (int r = 0; r < 16; ++r) {
        size_t row = (size_t)(r0 + g * 16 + r);
        xw[row * OUT_F + lane]        = acc[r][0];
        xw[row * OUT_F + lane + 64]   = acc[r][1];
        xw[row * OUT_F + lane + 128]  = acc[r][2];
        xw[row * OUT_F + lane + 192]  = acc[r][3];
    }
}

// -------- K3: emb = relu(adj @ XW); out = emb @ w_lin + b -------------------
__global__ __launch_bounds__(256) void k3_emb_out(
    const float* __restrict__ xw, const float* __restrict__ wl,
    const float* __restrict__ bl, float* __restrict__ out_base)
{
    unsigned h = blockIdx.x;
    unsigned xcd = h & 7u;
    unsigned q = h >> 3;
    unsigned b = xcd * 32u + q / N_SZ;
    unsigned i = q % N_SZ;

    const int tid = threadIdx.x;
    const float* adj = out_base + ADJ_OFF + (size_t)b * NN + (size_t)i * N_SZ;

    __shared__ unsigned long long masks[4];
    __shared__ float red[4][NCLS];

    bool selb = false;
    if (tid < N_SZ) selb = (adj[tid] != 0.0f);
    unsigned long long m = __ballot(selb);
    const int wave = tid >> 6;
    const int lane = tid & 63;
    if (lane == 0) masks[wave] = m;
    __syncthreads();

    float acc = 0.0f;
    const float* xwb = xw + (size_t)b * N_SZ * OUT_F;
    #pragma unroll 1
    for (int w = 0; w < 4; ++w) {
        unsigned long long mm = masks[w];
        while (mm) {
            int bit = __builtin_ctzll(mm);
            int jj = w * 64 + bit;
            acc += xwb[(size_t)jj * OUT_F + tid];
            mm &= mm - 1;
        }
    }
    float emb = fmaxf(acc, 0.0f);
    out_base[EMB_OFF + ((size_t)b * N_SZ + i) * OUT_F + tid] = emb;

    float p[NCLS];
    #pragma unroll
    for (int c = 0; c < NCLS; ++c) p[c] = emb * wl[tid * NCLS + c];
    #pragma unroll
    for (int c = 0; c < NCLS; ++c) {
        #pragma unroll
        for (int off = 32; off >= 1; off >>= 1)
            p[c] += __shfl_xor(p[c], off, 64);
    }
    if (lane == 0) {
        #pragma unroll
        for (int c = 0; c < NCLS; ++c) red[wave][c] = p[c];
    }
    __syncthreads();
    if (tid < NCLS) {
        float s = red[0][tid] + red[1][tid] + red[2][tid] + red[3][tid] + bl[tid];
        out_base[((size_t)b * N_SZ + i) * NCLS + tid] = s;
    }
}

extern "C" void kernel_launch(void* const* d_in, const int* in_sizes, int n_in,
                              void* d_out, int out_size, void* d_ws, size_t ws_size,
                              hipStream_t stream) {
    const float* x    = (const float*)d_in[0];
    const float* gu   = (const float*)d_in[1];
    const float* nets = (const float*)d_in[2];
    const float* wg   = (const float*)d_in[3];
    const float* wl   = (const float*)d_in[4];
    const float* bl   = (const float*)d_in[5];
    const int*   nidx = (const int*)d_in[6];
    float* out = (float*)d_out;

    char* ws = (char*)d_ws;
    unsigned* keys    = (unsigned*)(ws + KEYS_OFF_B);
    unsigned* hist    = (unsigned*)(ws + HIST_OFF_B);     // 4 rounds x B x 256
    unsigned* sel     = (unsigned*)(ws + SEL_OFF_B);
    unsigned* candCnt = (unsigned*)(ws + CCNT_OFF_B);
    unsigned* cand    = (unsigned*)(ws + CAND_OFF_B);
    float* xw = (float*)d_ws;   // aliases keys; K2 runs after K1 chain

    hipMemsetAsync(ws + HIST_OFF_B, 0, MEMSET_LEN, stream);

    kA<<<B_SZ * NTILES, 256, 0, stream>>>(gu, nets, nidx, keys, hist);
    kSel<<<B_SZ, 256, 0, stream>>>(hist, sel, 0);
    kScan<<<B_SZ * SCAN_CH, 256, 0, stream>>>(keys, sel, hist + 256 * B_SZ, 16);
    kSel<<<B_SZ, 256, 0, stream>>>(hist + 256 * B_SZ, sel, 1);
    kScan<<<B_SZ * SCAN_CH, 256, 0, stream>>>(keys, sel, hist + 2 * 256 * B_SZ, 8);
    kSel<<<B_SZ, 256, 0, stream>>>(hist + 2 * 256 * B_SZ, sel, 2);
    kScan<<<B_SZ * SCAN_CH, 256, 0, stream>>>(keys, sel, hist + 3 * 256 * B_SZ, 0);
    kSel<<<B_SZ, 256, 0, stream>>>(hist + 3 * 256 * B_SZ, sel, 3);
    kW<<<B_SZ * NTILES, 256, 0, stream>>>(keys, sel, candCnt, cand, out);
    kT<<<B_SZ, 64, 0, stream>>>(sel, candCnt, cand, out);

    k2_xw<<<(B_SZ * N_SZ) / 64, 256, 0, stream>>>(x, wg, xw);
    k3_emb_out<<<B_SZ * N_SZ, 256, 0, stream>>>(xw, wl, bl, out);
}

// Round 3
// 363.057 us; speedup vs baseline: 1.6222x; 1.2085x over previous
//
#include <hip/hip_runtime.h>
#include <math.h>

#define B_SZ 256
#define N_SZ 200
#define NN (N_SZ * N_SZ)          // 40000
#define FIN 200
#define OUT_F 256
#define NCLS 8
#define KSEL 3980
#define NUPPER 20100              // N*(N+1)/2
#define KSTRIDE 20128
#define NT 7                      // ceil(200/32) tiles per dim
#define NTILES 28                 // NT*(NT+1)/2 upper tile pairs
#define SCAN_CH 16
#define CAND_CAP 2048

#define EMB_OFF (B_SZ * N_SZ * NCLS)               // 409600
#define ADJ_OFF (EMB_OFF + B_SZ * N_SZ * OUT_F)    // 13516800

// ---- ws layout (bytes) ----
#define KEYS_OFF_B   0
#define HIST_OFF_B   20611072
#define SEL_OFF_B    21659648
#define CCNT_OFF_B   21661696
#define CAND_OFF_B   21662720
#define MEMSET_LEN   (1048576 + 2048 + 1024)

__device__ __forceinline__ unsigned sortkey(float f) {
    unsigned u = __float_as_uint(f);
    return (u & 0x80000000u) ? ~u : (u | 0x80000000u);
}

__device__ __forceinline__ void tile_decode(int t, int& ti, int& tj) {
    int a = 0, rem = t;
    while (rem >= NT - a) { rem -= NT - a; ++a; }
    ti = a; tj = a + rem;
}

// -------- kA: compute sym keys (packed upper-tri) + round-0 histogram -------
__global__ __launch_bounds__(256) void kA(
    const float* __restrict__ gu, const float* __restrict__ nets,
    const int* __restrict__ net_index, unsigned* __restrict__ keys,
    unsigned* __restrict__ hist0)
{
    const int blk = blockIdx.x;
    const int b = blk / NTILES;
    int ti, tj; tile_decode(blk % NTILES, ti, tj);
    const int i0 = ti * 32, j0 = tj * 32;
    const float* ub = gu + (size_t)b * NN;
    const float* lb = nets + (size_t)net_index[b] * NN;

    __shared__ float Hij[32][33];
    __shared__ float Hji[32][33];
    __shared__ unsigned hist[256];
    hist[threadIdx.x] = 0;

    const int r = threadIdx.x >> 5;
    const int c = threadIdx.x & 31;

    #pragma unroll
    for (int s = 0; s < 4; ++s) {
        int rr = r + 8 * s;
        int i = i0 + rr, j = j0 + c;
        if (i < N_SZ && j < N_SZ) {
            float u = ub[i * N_SZ + j];
            u = fminf(fmaxf(u, 1e-10f), 1.0f - 1e-10f);
            Hij[rr][c] = lb[i * N_SZ + j] - logf(-logf(u));
        }
        if (ti != tj) {
            int i2 = j0 + rr, j2 = i0 + c;
            if (i2 < N_SZ && j2 < N_SZ) {
                float u = ub[i2 * N_SZ + j2];
                u = fminf(fmaxf(u, 1e-10f), 1.0f - 1e-10f);
                Hji[rr][c] = lb[i2 * N_SZ + j2] - logf(-logf(u));
            }
        }
    }
    __syncthreads();

    unsigned* kb = keys + (size_t)b * KSTRIDE;
    #pragma unroll
    for (int s = 0; s < 4; ++s) {
        int rr = r + 8 * s;
        int i = i0 + rr, j = j0 + c;
        if (i < N_SZ && j < N_SZ && i <= j) {
            float hji = (ti == tj) ? Hij[c][rr] : Hji[c][rr];
            float sv = 0.5f * (Hij[rr][c] + hji);
            unsigned key = sortkey(sv);
            int base = i * N_SZ - (i * (i - 1)) / 2;
            kb[base + (j - i)] = key;
            atomicAdd(&hist[key >> 24], 1u);
        }
    }
    __syncthreads();
    if (hist[threadIdx.x]) atomicAdd(&hist0[b * 256 + threadIdx.x], hist[threadIdx.x]);
}

// -------- kSel: pick bucket for this round, update (prefix, kk) -------------
__global__ __launch_bounds__(256) void kSel(
    const unsigned* __restrict__ histr, unsigned* __restrict__ sel, int round)
{
    const int b = blockIdx.x;
    __shared__ unsigned h[256];
    h[threadIdx.x] = histr[b * 256 + threadIdx.x];
    __syncthreads();
    if (threadIdx.x == 0) {
        int kk = (round == 0) ? KSEL : (int)sel[b * 2 + 1];
        unsigned prefix = (round == 0) ? 0u : sel[b * 2];
        int cum = 0; int bsel = 0;
        for (int bn = 255; bn >= 0; --bn) {
            int cc = (int)h[bn];
            if (cum + cc >= kk) { bsel = bn; kk = kk - cum; break; }
            cum += cc;
        }
        sel[b * 2] = (prefix << 8) | (unsigned)bsel;
        sel[b * 2 + 1] = (unsigned)kk;
    }
}

// -------- kScan: histogram next byte among keys matching current prefix -----
__global__ __launch_bounds__(256) void kScan(
    const unsigned* __restrict__ keys, const unsigned* __restrict__ sel,
    unsigned* __restrict__ histr, int shift)
{
    const int blk = blockIdx.x;
    const int b = blk / SCAN_CH;
    const int ch = blk % SCAN_CH;
    const unsigned prefix = sel[b * 2];
    __shared__ unsigned hist[256];
    hist[threadIdx.x] = 0;
    __syncthreads();
    const unsigned* kb = keys + (size_t)b * KSTRIDE;
    const int per = (NUPPER + SCAN_CH - 1) / SCAN_CH;
    const int lo = ch * per;
    const int hi = (lo + per < NUPPER) ? lo + per : NUPPER;
    for (int idx = lo + threadIdx.x; idx < hi; idx += 256) {
        unsigned key = kb[idx];
        if ((key >> (shift + 8)) == prefix)
            atomicAdd(&hist[(key >> shift) & 255u], 1u);
    }
    __syncthreads();
    if (hist[threadIdx.x]) atomicAdd(&histr[b * 256 + threadIdx.x], hist[threadIdx.x]);
}

// -------- kW: write full 0/1 adj (both triangles), collect exact ties -------
__global__ __launch_bounds__(256) void kW(
    const unsigned* __restrict__ keys, const unsigned* __restrict__ sel,
    unsigned* __restrict__ candCnt, unsigned* __restrict__ cand,
    float* __restrict__ out_base)
{
    const int blk = blockIdx.x;
    const int b = blk / NTILES;
    int ti, tj; tile_decode(blk % NTILES, ti, tj);
    const int i0 = ti * 32, j0 = tj * 32;
    const unsigned kth = sel[b * 2];
    const unsigned* kb = keys + (size_t)b * KSTRIDE;
    float* adj = out_base + ADJ_OFF + (size_t)b * NN;

    __shared__ float V[32][33];
    const int r = threadIdx.x >> 5;
    const int c = threadIdx.x & 31;

    #pragma unroll
    for (int s = 0; s < 4; ++s) {
        int rr = r + 8 * s;
        int i = i0 + rr, j = j0 + c;
        if (i < N_SZ && j < N_SZ && i <= j) {
            int base = i * N_SZ - (i * (i - 1)) / 2;
            unsigned key = kb[base + (j - i)];
            float v = (key > kth) ? 1.0f : 0.0f;
            if (key == kth) {
                unsigned p = atomicAdd(&candCnt[b], 1u);
                if (p < CAND_CAP) cand[(size_t)b * CAND_CAP + p] = (unsigned)(i * N_SZ + j);
            }
            V[rr][c] = v;
            if (ti == tj) V[c][rr] = v;
        }
    }
    __syncthreads();
    #pragma unroll
    for (int s = 0; s < 4; ++s) {
        int rr = r + 8 * s;
        int i = i0 + rr, j = j0 + c;
        if (i < N_SZ && j < N_SZ) adj[i * N_SZ + j] = V[rr][c];
    }
    if (ti != tj) {
        #pragma unroll
        for (int s = 0; s < 4; ++s) {
            int rr = r + 8 * s;
            int i2 = j0 + rr, j2 = i0 + c;
            if (i2 < N_SZ && j2 < N_SZ) adj[i2 * N_SZ + j2] = V[c][rr];
        }
    }
}

// -------- kT: deterministically include first-kk ties by flat index ---------
__global__ void kT(const unsigned* __restrict__ sel,
                   const unsigned* __restrict__ candCnt,
                   const unsigned* __restrict__ cand,
                   float* __restrict__ out_base)
{
    const int b = blockIdx.x;
    if (threadIdx.x != 0) return;
    int kk = (int)sel[b * 2 + 1];
    int cnt = (int)candCnt[b];
    if (cnt > CAND_CAP) cnt = CAND_CAP;
    float* adj = out_base + ADJ_OFF + (size_t)b * NN;
    int take = kk < cnt ? kk : cnt;
    unsigned used[64];
    int nu = 0;
    for (int t = 0; t < take; ++t) {
        unsigned best = 0xFFFFFFFFu;
        for (int q = 0; q < cnt; ++q) {
            unsigned v = cand[(size_t)b * CAND_CAP + q];
            bool skip = false;
            for (int u = 0; u < nu; ++u) if (used[u] == v) { skip = true; break; }
            if (!skip && v < best) best = v;
        }
        if (best == 0xFFFFFFFFu) break;
        if (nu < 64) used[nu++] = best;
        int i = (int)(best / N_SZ), j = (int)(best % N_SZ);
        adj[i * N_SZ + j] = 1.0f;
        adj[j * N_SZ + i] = 1.0f;
    }
}

// -------- K2: XW = x @ w_gnn  ([51200 x 200] @ [200 x 256]) -----------------
__global__ __launch_bounds__(256) void k2_xw(
    const float* __restrict__ x, const float* __restrict__ wg,
    float* __restrict__ xw)
{
    __shared__ float xs[64][FIN];
    const int tid = threadIdx.x;
    const int r0 = blockIdx.x * 64;
    for (int t = tid; t < 64 * FIN; t += 256) {
        int r = t / FIN, c = t % FIN;
        xs[r][c] = x[(size_t)(r0 + r) * FIN + c];
    }
    __syncthreads();
    const int g = tid >> 6;
    const int lane = tid & 63;
    float acc[16][4];
    #pragma unroll
    for (int r = 0; r < 16; ++r)
        #pragma unroll
        for (int c = 0; c < 4; ++c) acc[r][c] = 0.0f;

    for (int k = 0; k < FIN; ++k) {
        float wv0 = wg[k * OUT_F + lane];
        float wv1 = wg[k * OUT_F + lane + 64];
        float wv2 = wg[k * OUT_F + lane + 128];
        float wv3 = wg[k * OUT_F + lane + 192];
        #pragma unroll
        for (int r = 0; r < 16; ++r) {
            float xv = xs[g * 16 + r][k];
            acc[r][0] += xv * wv0;
            acc[r][1] += xv * wv1;
            acc[r][2] += xv * wv2;
            acc[r][3] += xv * wv3;
        }
    }
    #pragma unroll
    for (int r = 0; r < 16; ++r) {
        size_t row = (size_t)(r0 + g * 16 + r);
        xw[row * OUT_F + lane]        = acc[r][0];
        xw[row * OUT_F + lane + 64]   = acc[r][1];
        xw[row * OUT_F + lane + 128]  = acc[r][2];
        xw[row * OUT_F + lane + 192]  = acc[r][3];
    }
}

// -------- K3: emb = relu(adj @ XW); out = emb @ w_lin + b -------------------
// Index-list + 8-wide MLP accumulation (4 independent accumulators).
__global__ __launch_bounds__(256) void k3_emb_out(
    const float* __restrict__ xw, const float* __restrict__ wl,
    const float* __restrict__ bl, float* __restrict__ out_base)
{
    unsigned h = blockIdx.x;
    unsigned xcd = h & 7u;
    unsigned q = h >> 3;
    unsigned b = xcd * 32u + q / N_SZ;
    unsigned i = q % N_SZ;

    const int tid = threadIdx.x;
    const int wave = tid >> 6;
    const int lane = tid & 63;
    const float* adj = out_base + ADJ_OFF + (size_t)b * NN + (size_t)i * N_SZ;

    __shared__ unsigned long long masks[4];
    __shared__ unsigned pfx[4];
    __shared__ int scnt;
    __shared__ unsigned short idxs[256];
    __shared__ float red[4][NCLS];

    bool selb = (tid < N_SZ) && (adj[tid] != 0.0f);
    unsigned long long m = __ballot(selb);
    if (lane == 0) masks[wave] = m;
    __syncthreads();
    if (tid == 0) {
        unsigned s = 0;
        #pragma unroll
        for (int w = 0; w < 4; ++w) { pfx[w] = s; s += (unsigned)__popcll(masks[w]); }
        scnt = (int)s;
    }
    __syncthreads();
    if (selb) {
        unsigned long long below = masks[wave] & ((lane == 0) ? 0ull : (~0ull >> (64 - lane)));
        idxs[pfx[wave] + (unsigned)__popcll(below)] = (unsigned short)tid;
    }
    __syncthreads();

    const int cnt = scnt;
    const float* xwb = xw + (size_t)b * N_SZ * OUT_F + tid;
    float a0 = 0.0f, a1 = 0.0f, a2 = 0.0f, a3 = 0.0f;
    int p = 0;
    for (; p + 8 <= cnt; p += 8) {
        int j0 = idxs[p + 0], j1 = idxs[p + 1], j2 = idxs[p + 2], j3 = idxs[p + 3];
        int j4 = idxs[p + 4], j5 = idxs[p + 5], j6 = idxs[p + 6], j7 = idxs[p + 7];
        float v0 = xwb[(size_t)j0 * OUT_F];
        float v1 = xwb[(size_t)j1 * OUT_F];
        float v2 = xwb[(size_t)j2 * OUT_F];
        float v3 = xwb[(size_t)j3 * OUT_F];
        float v4 = xwb[(size_t)j4 * OUT_F];
        float v5 = xwb[(size_t)j5 * OUT_F];
        float v6 = xwb[(size_t)j6 * OUT_F];
        float v7 = xwb[(size_t)j7 * OUT_F];
        a0 += v0 + v4;
        a1 += v1 + v5;
        a2 += v2 + v6;
        a3 += v3 + v7;
    }
    for (; p < cnt; ++p) a0 += xwb[(size_t)idxs[p] * OUT_F];
    float emb = fmaxf((a0 + a1) + (a2 + a3), 0.0f);
    out_base[EMB_OFF + ((size_t)b * N_SZ + i) * OUT_F + tid] = emb;

    float pr[NCLS];
    #pragma unroll
    for (int c = 0; c < NCLS; ++c) pr[c] = emb * wl[tid * NCLS + c];
    #pragma unroll
    for (int c = 0; c < NCLS; ++c) {
        #pragma unroll
        for (int off = 32; off >= 1; off >>= 1)
            pr[c] += __shfl_xor(pr[c], off, 64);
    }
    if (lane == 0) {
        #pragma unroll
        for (int c = 0; c < NCLS; ++c) red[wave][c] = pr[c];
    }
    __syncthreads();
    if (tid < NCLS) {
        float s = red[0][tid] + red[1][tid] + red[2][tid] + red[3][tid] + bl[tid];
        out_base[((size_t)b * N_SZ + i) * NCLS + tid] = s;
    }
}

extern "C" void kernel_launch(void* const* d_in, const int* in_sizes, int n_in,
                              void* d_out, int out_size, void* d_ws, size_t ws_size,
                              hipStream_t stream) {
    const float* x    = (const float*)d_in[0];
    const float* gu   = (const float*)d_in[1];
    const float* nets = (const float*)d_in[2];
    const float* wg   = (const float*)d_in[3];
    const float* wl   = (const float*)d_in[4];
    const float* bl   = (const float*)d_in[5];
    const int*   nidx = (const int*)d_in[6];
    float* out = (float*)d_out;

    char* ws = (char*)d_ws;
    unsigned* keys    = (unsigned*)(ws + KEYS_OFF_B);
    unsigned* hist    = (unsigned*)(ws + HIST_OFF_B);
    unsigned* sel     = (unsigned*)(ws + SEL_OFF_B);
    unsigned* candCnt = (unsigned*)(ws + CCNT_OFF_B);
    unsigned* cand    = (unsigned*)(ws + CAND_OFF_B);
    float* xw = (float*)d_ws;   // aliases keys; K2 runs after K1 chain

    hipMemsetAsync(ws + HIST_OFF_B, 0, MEMSET_LEN, stream);

    kA<<<B_SZ * NTILES, 256, 0, stream>>>(gu, nets, nidx, keys, hist);
    kSel<<<B_SZ, 256, 0, stream>>>(hist, sel, 0);
    kScan<<<B_SZ * SCAN_CH, 256, 0, stream>>>(keys, sel, hist + 256 * B_SZ, 16);
    kSel<<<B_SZ, 256, 0, stream>>>(hist + 256 * B_SZ, sel, 1);
    kScan<<<B_SZ * SCAN_CH, 256, 0, stream>>>(keys, sel, hist + 2 * 256 * B_SZ, 8);
    kSel<<<B_SZ, 256, 0, stream>>>(hist + 2 * 256 * B_SZ, sel, 2);
    kScan<<<B_SZ * SCAN_CH, 256, 0, stream>>>(keys, sel, hist + 3 * 256 * B_SZ, 0);
    kSel<<<B_SZ, 256, 0, stream>>>(hist + 3 * 256 * B_SZ, sel, 3);
    kW<<<B_SZ * NTILES, 256, 0, stream>>>(keys, sel, candCnt, cand, out);
    kT<<<B_SZ, 64, 0, stream>>>(sel, candCnt, cand, out);

    k2_xw<<<(B_SZ * N_SZ) / 64, 256, 0, stream>>>(x, wg, xw);
    k3_emb_out<<<B_SZ * N_SZ, 256, 0, stream>>>(xw, wl, bl, out);
}

// Round 4
// 359.920 us; speedup vs baseline: 1.6364x; 1.0087x over previous
//
#include <hip/hip_runtime.h>
#include <math.h>

#define B_SZ 256
#define N_SZ 200
#define NN (N_SZ * N_SZ)          // 40000
#define FIN 200
#define OUT_F 256
#define NCLS 8
#define KSEL 3980
#define NUPPER 20100              // N*(N+1)/2
#define KSTRIDE 20128
#define NT 7                      // ceil(200/32) tiles per dim
#define NTILES 28                 // NT*(NT+1)/2 upper tile pairs
#define SCAN_CH 16
#define CAND_CAP 2048

#define ADJ_STRIDE 224            // adj_bf16 row stride (K-padded, zeros beyond 199)
#define KGRP_PB 25                // kgroups per batch (200/8)
#define XWM_PB (KGRP_PB * 2048)   // 51200 elems per batch in mfma layout

#define EMB_OFF (B_SZ * N_SZ * NCLS)               // 409600
#define ADJ_OFF (EMB_OFF + B_SZ * N_SZ * OUT_F)    // 13516800

// ---- ws layout (bytes) ----
// keys:     [0, 20,611,072)        dead after kW  -- aliased by XW_mfma
// hist:     [20,611,072, +1MB)     dead after kT  -- partially aliased later
// sel/cand: [...]                  dead after kT
// XW_mfma:  [0, 26,214,400)        written by k2 (after kT), read by k3
// adj_bf16: [26,301,440, +22,937,600) = end 49.24 MB
#define KEYS_OFF_B   0
#define HIST_OFF_B   20611072
#define SEL_OFF_B    21659648
#define CCNT_OFF_B   21661696
#define CAND_OFF_B   21662720
#define ADJB16_OFF_B 26301440
#define MEMSET_LEN   (1048576 + 2048 + 1024)

typedef unsigned short ushort_t;
typedef float f32x4 __attribute__((ext_vector_type(4)));
typedef short bf16x8 __attribute__((ext_vector_type(8)));

__device__ __forceinline__ unsigned sortkey(float f) {
    unsigned u = __float_as_uint(f);
    return (u & 0x80000000u) ? ~u : (u | 0x80000000u);
}

__device__ __forceinline__ ushort_t f2b(float f) {   // RNE fp32->bf16
    unsigned u = __float_as_uint(f);
    return (ushort_t)((u + 0x7FFFu + ((u >> 16) & 1u)) >> 16);
}

__device__ __forceinline__ void tile_decode(int t, int& ti, int& tj) {
    int a = 0, rem = t;
    while (rem >= NT - a) { rem -= NT - a; ++a; }
    ti = a; tj = a + rem;
}

// -------- kA: compute sym keys (packed upper-tri) + round-0 histogram -------
__global__ __launch_bounds__(256) void kA(
    const float* __restrict__ gu, const float* __restrict__ nets,
    const int* __restrict__ net_index, unsigned* __restrict__ keys,
    unsigned* __restrict__ hist0)
{
    const int blk = blockIdx.x;
    const int b = blk / NTILES;
    int ti, tj; tile_decode(blk % NTILES, ti, tj);
    const int i0 = ti * 32, j0 = tj * 32;
    const float* ub = gu + (size_t)b * NN;
    const float* lb = nets + (size_t)net_index[b] * NN;

    __shared__ float Hij[32][33];
    __shared__ float Hji[32][33];
    __shared__ unsigned hist[256];
    hist[threadIdx.x] = 0;

    const int r = threadIdx.x >> 5;
    const int c = threadIdx.x & 31;

    #pragma unroll
    for (int s = 0; s < 4; ++s) {
        int rr = r + 8 * s;
        int i = i0 + rr, j = j0 + c;
        if (i < N_SZ && j < N_SZ) {
            float u = ub[i * N_SZ + j];
            u = fminf(fmaxf(u, 1e-10f), 1.0f - 1e-10f);
            Hij[rr][c] = lb[i * N_SZ + j] - logf(-logf(u));
        }
        if (ti != tj) {
            int i2 = j0 + rr, j2 = i0 + c;
            if (i2 < N_SZ && j2 < N_SZ) {
                float u = ub[i2 * N_SZ + j2];
                u = fminf(fmaxf(u, 1e-10f), 1.0f - 1e-10f);
                Hji[rr][c] = lb[i2 * N_SZ + j2] - logf(-logf(u));
            }
        }
    }
    __syncthreads();

    unsigned* kb = keys + (size_t)b * KSTRIDE;
    #pragma unroll
    for (int s = 0; s < 4; ++s) {
        int rr = r + 8 * s;
        int i = i0 + rr, j = j0 + c;
        if (i < N_SZ && j < N_SZ && i <= j) {
            float hji = (ti == tj) ? Hij[c][rr] : Hji[c][rr];
            float sv = 0.5f * (Hij[rr][c] + hji);
            unsigned key = sortkey(sv);
            int base = i * N_SZ - (i * (i - 1)) / 2;
            kb[base + (j - i)] = key;
            atomicAdd(&hist[key >> 24], 1u);
        }
    }
    __syncthreads();
    if (hist[threadIdx.x]) atomicAdd(&hist0[b * 256 + threadIdx.x], hist[threadIdx.x]);
}

// -------- kSel: pick bucket for this round, update (prefix, kk) -------------
__global__ __launch_bounds__(256) void kSel(
    const unsigned* __restrict__ histr, unsigned* __restrict__ sel, int round)
{
    const int b = blockIdx.x;
    __shared__ unsigned h[256];
    h[threadIdx.x] = histr[b * 256 + threadIdx.x];
    __syncthreads();
    if (threadIdx.x == 0) {
        int kk = (round == 0) ? KSEL : (int)sel[b * 2 + 1];
        unsigned prefix = (round == 0) ? 0u : sel[b * 2];
        int cum = 0; int bsel = 0;
        for (int bn = 255; bn >= 0; --bn) {
            int cc = (int)h[bn];
            if (cum + cc >= kk) { bsel = bn; kk = kk - cum; break; }
            cum += cc;
        }
        sel[b * 2] = (prefix << 8) | (unsigned)bsel;
        sel[b * 2 + 1] = (unsigned)kk;
    }
}

// -------- kScan: histogram next byte among keys matching current prefix -----
__global__ __launch_bounds__(256) void kScan(
    const unsigned* __restrict__ keys, const unsigned* __restrict__ sel,
    unsigned* __restrict__ histr, int shift)
{
    const int blk = blockIdx.x;
    const int b = blk / SCAN_CH;
    const int ch = blk % SCAN_CH;
    const unsigned prefix = sel[b * 2];
    __shared__ unsigned hist[256];
    hist[threadIdx.x] = 0;
    __syncthreads();
    const unsigned* kb = keys + (size_t)b * KSTRIDE;
    const int per = (NUPPER + SCAN_CH - 1) / SCAN_CH;
    const int lo = ch * per;
    const int hi = (lo + per < NUPPER) ? lo + per : NUPPER;
    for (int idx = lo + threadIdx.x; idx < hi; idx += 256) {
        unsigned key = kb[idx];
        if ((key >> (shift + 8)) == prefix)
            atomicAdd(&hist[(key >> shift) & 255u], 1u);
    }
    __syncthreads();
    if (hist[threadIdx.x]) atomicAdd(&histr[b * 256 + threadIdx.x], hist[threadIdx.x]);
}

// -------- kW: write 0/1 adj (fp32 + bf16 K-padded), collect exact ties ------
__global__ __launch_bounds__(256) void kW(
    const unsigned* __restrict__ keys, const unsigned* __restrict__ sel,
    unsigned* __restrict__ candCnt, unsigned* __restrict__ cand,
    float* __restrict__ out_base, ushort_t* __restrict__ adjb16)
{
    const int blk = blockIdx.x;
    const int b = blk / NTILES;
    int ti, tj; tile_decode(blk % NTILES, ti, tj);
    const int i0 = ti * 32, j0 = tj * 32;
    const unsigned kth = sel[b * 2];
    const unsigned* kb = keys + (size_t)b * KSTRIDE;
    float* adj = out_base + ADJ_OFF + (size_t)b * NN;
    ushort_t* ab = adjb16 + (size_t)b * (N_SZ * ADJ_STRIDE);

    __shared__ float V[32][33];
    const int r = threadIdx.x >> 5;
    const int c = threadIdx.x & 31;

    #pragma unroll
    for (int s = 0; s < 4; ++s) {
        int rr = r + 8 * s;
        int i = i0 + rr, j = j0 + c;
        if (i < N_SZ && j < N_SZ && i <= j) {
            int base = i * N_SZ - (i * (i - 1)) / 2;
            unsigned key = kb[base + (j - i)];
            float v = (key > kth) ? 1.0f : 0.0f;
            if (key == kth) {
                unsigned p = atomicAdd(&candCnt[b], 1u);
                if (p < CAND_CAP) cand[(size_t)b * CAND_CAP + p] = (unsigned)(i * N_SZ + j);
            }
            V[rr][c] = v;
            if (ti == tj) V[c][rr] = v;
        }
    }
    __syncthreads();
    #pragma unroll
    for (int s = 0; s < 4; ++s) {
        int rr = r + 8 * s;
        int i = i0 + rr, j = j0 + c;
        if (i < N_SZ) {
            float v = (j < N_SZ) ? V[rr][c] : 0.0f;
            if (j < N_SZ) adj[i * N_SZ + j] = v;
            ab[i * ADJ_STRIDE + j] = (v != 0.0f) ? (ushort_t)0x3F80 : (ushort_t)0;
        }
    }
    if (ti != tj) {
        #pragma unroll
        for (int s = 0; s < 4; ++s) {
            int rr = r + 8 * s;
            int i2 = j0 + rr, j2 = i0 + c;
            if (i2 < N_SZ) {
                float v = V[c][rr];
                adj[i2 * N_SZ + j2] = v;
                ab[i2 * ADJ_STRIDE + j2] = (v != 0.0f) ? (ushort_t)0x3F80 : (ushort_t)0;
            }
        }
    }
}

// -------- kT: deterministically include first-kk ties by flat index ---------
__global__ void kT(const unsigned* __restrict__ sel,
                   const unsigned* __restrict__ candCnt,
                   const unsigned* __restrict__ cand,
                   float* __restrict__ out_base, ushort_t* __restrict__ adjb16)
{
    const int b = blockIdx.x;
    if (threadIdx.x != 0) return;
    int kk = (int)sel[b * 2 + 1];
    int cnt = (int)candCnt[b];
    if (cnt > CAND_CAP) cnt = CAND_CAP;
    float* adj = out_base + ADJ_OFF + (size_t)b * NN;
    ushort_t* ab = adjb16 + (size_t)b * (N_SZ * ADJ_STRIDE);
    int take = kk < cnt ? kk : cnt;
    unsigned used[64];
    int nu = 0;
    for (int t = 0; t < take; ++t) {
        unsigned best = 0xFFFFFFFFu;
        for (int q = 0; q < cnt; ++q) {
            unsigned v = cand[(size_t)b * CAND_CAP + q];
            bool skip = false;
            for (int u = 0; u < nu; ++u) if (used[u] == v) { skip = true; break; }
            if (!skip && v < best) best = v;
        }
        if (best == 0xFFFFFFFFu) break;
        if (nu < 64) used[nu++] = best;
        int i = (int)(best / N_SZ), j = (int)(best % N_SZ);
        adj[i * N_SZ + j] = 1.0f;
        adj[j * N_SZ + i] = 1.0f;
        ab[i * ADJ_STRIDE + j] = (ushort_t)0x3F80;
        ab[j * ADJ_STRIDE + i] = (ushort_t)0x3F80;
    }
}

// -------- K2: XW = x @ w_gnn (fp32 math) -> bf16 mfma-layout ----------------
// XW_mfma[b]: [25 kgrp][256 n][8 kin] bf16, elem off = b*51200 + (k>>3)*2048 + n*8 + (k&7)
__global__ __launch_bounds__(256) void k2_xw(
    const float* __restrict__ x, const float* __restrict__ wg,
    ushort_t* __restrict__ xwm)
{
    __shared__ float xs[64][FIN];
    const int tid = threadIdx.x;
    const int r0 = blockIdx.x * 64;
    for (int t = tid; t < 64 * FIN; t += 256) {
        int r = t / FIN, c = t % FIN;
        xs[r][c] = x[(size_t)(r0 + r) * FIN + c];
    }
    __syncthreads();
    const int g = tid >> 6;
    const int lane = tid & 63;
    float acc[16][4];
    #pragma unroll
    for (int r = 0; r < 16; ++r)
        #pragma unroll
        for (int c = 0; c < 4; ++c) acc[r][c] = 0.0f;

    for (int k = 0; k < FIN; ++k) {
        float wv0 = wg[k * OUT_F + lane];
        float wv1 = wg[k * OUT_F + lane + 64];
        float wv2 = wg[k * OUT_F + lane + 128];
        float wv3 = wg[k * OUT_F + lane + 192];
        #pragma unroll
        for (int r = 0; r < 16; ++r) {
            float xv = xs[g * 16 + r][k];
            acc[r][0] += xv * wv0;
            acc[r][1] += xv * wv1;
            acc[r][2] += xv * wv2;
            acc[r][3] += xv * wv3;
        }
    }
    __syncthreads();
    // scatter bf16 into mfma layout in LDS (reuse xs, 32 KB needed)
    ushort_t* tb = (ushort_t*)xs;
    #pragma unroll
    for (int r = 0; r < 16; ++r) {
        int rl = g * 16 + r;
        #pragma unroll
        for (int c = 0; c < 4; ++c) {
            int col = lane + 64 * c;
            tb[((rl >> 3) << 11) + (col << 3) + (rl & 7)] = f2b(acc[r][c]);
        }
    }
    __syncthreads();
    // linear write-out: 8 local kgroups -> global (64 rows = 8 kgrp, 200%8==0)
    #pragma unroll
    for (int kg = 0; kg < 8; ++kg) {
        int grow0 = r0 + kg * 8;
        int bb = grow0 / 200;
        int kb = grow0 % 200;
        ushort_t* dst = xwm + (size_t)bb * XWM_PB + ((kb >> 3) << 11);
        *(int4*)(dst + tid * 8) = *(const int4*)(tb + (kg << 11) + tid * 8);
    }
}

// -------- K3: emb = relu(adj @ XW) via bf16 MFMA ----------------------------
// block = (batch, 64-row mtile); 4 waves = 64-col quadrants; 7 K-chunks of 32
__global__ __launch_bounds__(256) void k3_mfma(
    const ushort_t* __restrict__ adjb16, const ushort_t* __restrict__ xwm,
    float* __restrict__ out_base)
{
    const int blk = blockIdx.x;
    const int b = blk >> 2;
    const int mt = blk & 3;
    const int tid = threadIdx.x;
    const int w = tid >> 6;
    const int l = tid & 63;
    const int g = l >> 4;
    const int r = l & 15;

    __shared__ ushort_t As[64 * 32];      // [64 rows][32 k] linear
    __shared__ ushort_t Bs[4 * 2048];     // [4 kgrp][256 n][8 kin]

    const ushort_t* adjb = adjb16 + (size_t)b * (N_SZ * ADJ_STRIDE);
    const ushort_t* xwb = xwm + (size_t)b * XWM_PB;

    f32x4 acc[4][4];
    #pragma unroll
    for (int mf = 0; mf < 4; ++mf)
        #pragma unroll
        for (int nf = 0; nf < 4; ++nf)
            acc[mf][nf] = (f32x4){0.f, 0.f, 0.f, 0.f};

    const int arow = tid >> 2;
    int grow = mt * 64 + arow;
    if (grow > N_SZ - 1) grow = N_SZ - 1;      // clamp; extra rows discarded
    const ushort_t* agp = adjb + grow * ADJ_STRIDE + (tid & 3) * 8;

    for (int c = 0; c < 7; ++c) {
        // prefetch to regs
        int4 av = *(const int4*)(agp + c * 32);
        int4 bv0 = *(const int4*)(xwb + c * 8192 + (0 * 256 + tid) * 8);
        int4 bv1 = *(const int4*)(xwb + c * 8192 + (1 * 256 + tid) * 8);
        int4 bv2 = *(const int4*)(xwb + c * 8192 + (2 * 256 + tid) * 8);
        int4 bv3 = *(const int4*)(xwb + c * 8192 + (3 * 256 + tid) * 8);
        __syncthreads();                       // prev chunk reads done
        *(int4*)(As + tid * 8) = av;
        *(int4*)(Bs + (0 * 256 + tid) * 8) = bv0;
        *(int4*)(Bs + (1 * 256 + tid) * 8) = bv1;
        *(int4*)(Bs + (2 * 256 + tid) * 8) = bv2;
        *(int4*)(Bs + (3 * 256 + tid) * 8) = bv3;
        __syncthreads();

        bf16x8 af[4], bf[4];
        #pragma unroll
        for (int mf = 0; mf < 4; ++mf)
            af[mf] = *(const bf16x8*)(As + (mf * 16 + r) * 32 + g * 8);
        #pragma unroll
        for (int nf = 0; nf < 4; ++nf)
            bf[nf] = *(const bf16x8*)(Bs + g * 2048 + (w * 64 + nf * 16 + r) * 8);
        #pragma unroll
        for (int mf = 0; mf < 4; ++mf)
            #pragma unroll
            for (int nf = 0; nf < 4; ++nf)
                acc[mf][nf] = __builtin_amdgcn_mfma_f32_16x16x32_bf16(
                    af[mf], bf[nf], acc[mf][nf], 0, 0, 0);
    }

    // epilogue: relu + store emb fp32
    #pragma unroll
    for (int mf = 0; mf < 4; ++mf) {
        #pragma unroll
        for (int j = 0; j < 4; ++j) {
            int rowl = mf * 16 + g * 4 + j;
            int grow2 = mt * 64 + rowl;
            if (grow2 < N_SZ) {
                size_t rbase = EMB_OFF + ((size_t)b * N_SZ + grow2) * OUT_F;
                #pragma unroll
                for (int nf = 0; nf < 4; ++nf) {
                    int col = w * 64 + nf * 16 + r;
                    out_base[rbase + col] = fmaxf(acc[mf][nf][j], 0.0f);
                }
            }
        }
    }
}

// -------- K4: out = emb @ w_lin + b ----------------------------------------
__global__ __launch_bounds__(256) void k4_out(
    const float* __restrict__ wl, const float* __restrict__ bl,
    float* __restrict__ out_base)
{
    const int row = blockIdx.x;               // 0..51199
    const int tid = threadIdx.x;
    const int wave = tid >> 6;
    const int lane = tid & 63;
    __shared__ float red[4][NCLS];

    float emb = out_base[EMB_OFF + (size_t)row * OUT_F + tid];
    float pr[NCLS];
    #pragma unroll
    for (int c = 0; c < NCLS; ++c) pr[c] = emb * wl[tid * NCLS + c];
    #pragma unroll
    for (int c = 0; c < NCLS; ++c) {
        #pragma unroll
        for (int off = 32; off >= 1; off >>= 1)
            pr[c] += __shfl_xor(pr[c], off, 64);
    }
    if (lane == 0) {
        #pragma unroll
        for (int c = 0; c < NCLS; ++c) red[wave][c] = pr[c];
    }
    __syncthreads();
    if (tid < NCLS) {
        float s = red[0][tid] + red[1][tid] + red[2][tid] + red[3][tid] + bl[tid];
        out_base[(size_t)row * NCLS + tid] = s;
    }
}

extern "C" void kernel_launch(void* const* d_in, const int* in_sizes, int n_in,
                              void* d_out, int out_size, void* d_ws, size_t ws_size,
                              hipStream_t stream) {
    const float* x    = (const float*)d_in[0];
    const float* gu   = (const float*)d_in[1];
    const float* nets = (const float*)d_in[2];
    const float* wg   = (const float*)d_in[3];
    const float* wl   = (const float*)d_in[4];
    const float* bl   = (const float*)d_in[5];
    const int*   nidx = (const int*)d_in[6];
    float* out = (float*)d_out;

    char* ws = (char*)d_ws;
    unsigned* keys    = (unsigned*)(ws + KEYS_OFF_B);
    unsigned* hist    = (unsigned*)(ws + HIST_OFF_B);
    unsigned* sel     = (unsigned*)(ws + SEL_OFF_B);
    unsigned* candCnt = (unsigned*)(ws + CCNT_OFF_B);
    unsigned* cand    = (unsigned*)(ws + CAND_OFF_B);
    ushort_t* xwm     = (ushort_t*)(ws + KEYS_OFF_B);   // aliases keys; k2 after kT
    ushort_t* adjb16  = (ushort_t*)(ws + ADJB16_OFF_B);

    hipMemsetAsync(ws + HIST_OFF_B, 0, MEMSET_LEN, stream);

    kA<<<B_SZ * NTILES, 256, 0, stream>>>(gu, nets, nidx, keys, hist);
    kSel<<<B_SZ, 256, 0, stream>>>(hist, sel, 0);
    kScan<<<B_SZ * SCAN_CH, 256, 0, stream>>>(keys, sel, hist + 256 * B_SZ, 16);
    kSel<<<B_SZ, 256, 0, stream>>>(hist + 256 * B_SZ, sel, 1);
    kScan<<<B_SZ * SCAN_CH, 256, 0, stream>>>(keys, sel, hist + 2 * 256 * B_SZ, 8);
    kSel<<<B_SZ, 256, 0, stream>>>(hist + 2 * 256 * B_SZ, sel, 2);
    kScan<<<B_SZ * SCAN_CH, 256, 0, stream>>>(keys, sel, hist + 3 * 256 * B_SZ, 0);
    kSel<<<B_SZ, 256, 0, stream>>>(hist + 3 * 256 * B_SZ, sel, 3);
    kW<<<B_SZ * NTILES, 256, 0, stream>>>(keys, sel, candCnt, cand, out, adjb16);
    kT<<<B_SZ, 64, 0, stream>>>(sel, candCnt, cand, out, adjb16);

    k2_xw<<<(B_SZ * N_SZ) / 64, 256, 0, stream>>>(x, wg, xwm);
    k3_mfma<<<B_SZ * 4, 256, 0, stream>>>(adjb16, xwm, out);
    k4_out<<<B_SZ * N_SZ, 256, 0, stream>>>(wl, bl, out);
}

// Round 5
// 249.550 us; speedup vs baseline: 2.3601x; 1.4423x over previous
//
#include <hip/hip_runtime.h>
#include <math.h>

#define B_SZ 256
#define N_SZ 200
#define NN (N_SZ * N_SZ)          // 40000
#define FIN 200
#define OUT_F 256
#define NCLS 8
#define KSEL 3980
#define NUPPER 20100              // N*(N+1)/2
#define KSTRIDE 20128
#define NT 7                      // ceil(200/32) tiles per dim
#define NTILES 28                 // NT*(NT+1)/2 upper tile pairs
#define SCAN_CH 16
#define CAND_CAP 2048

#define ADJ_STRIDE 224            // adj_bf16 row stride (K-padded, zeros beyond 199)
#define KGRP_PB 25                // kgroups per batch (200/8)
#define XWM_PB (KGRP_PB * 2048)   // 51200 elems per batch in mfma layout

#define EMB_OFF (B_SZ * N_SZ * NCLS)               // 409600
#define ADJ_OFF (EMB_OFF + B_SZ * N_SZ * OUT_F)    // 13516800

// ---- ws layout (bytes) ----
// keys:     [0, 20,611,072)            dead after kW -- aliased by XW_mfma
// hist/sel/cand: [20.6M, 23.76M)       dead after kT -- inside XWM region
// XW_mfma:  [0, 26,214,400)            written by k2 (after kT), read by k3
// w_kgrp:   [26,214,400, +114,688)     bf16 w in kgroup layout, 28 kgrp (3 zero)
// adj_bf16: [26,329,088, +22,937,600)  end 49,266,688 (< 52.4 MB proven in R1/R2)
#define KEYS_OFF_B   0
#define HIST_OFF_B   20611072
#define SEL_OFF_B    21659648
#define CCNT_OFF_B   21661696
#define CAND_OFF_B   21662720
#define WKG_OFF_B    26214400
#define ADJB16_OFF_B 26329088
#define MEMSET_LEN   (1048576 + 2048 + 1024)

typedef unsigned short ushort_t;
typedef float f32x4 __attribute__((ext_vector_type(4)));
typedef short bf16x8 __attribute__((ext_vector_type(8)));
typedef ushort_t u16x4 __attribute__((ext_vector_type(4)));

__device__ __forceinline__ unsigned sortkey(float f) {
    unsigned u = __float_as_uint(f);
    return (u & 0x80000000u) ? ~u : (u | 0x80000000u);
}

__device__ __forceinline__ ushort_t f2b(float f) {   // RNE fp32->bf16
    unsigned u = __float_as_uint(f);
    return (ushort_t)((u + 0x7FFFu + ((u >> 16) & 1u)) >> 16);
}

__device__ __forceinline__ u16x4 f2b4(float4 v) {
    u16x4 r;
    r.x = f2b(v.x); r.y = f2b(v.y); r.z = f2b(v.z); r.w = f2b(v.w);
    return r;
}

__device__ __forceinline__ void tile_decode(int t, int& ti, int& tj) {
    int a = 0, rem = t;
    while (rem >= NT - a) { rem -= NT - a; ++a; }
    ti = a; tj = a + rem;
}

// -------- kA: compute sym keys (packed upper-tri) + round-0 histogram -------
__global__ __launch_bounds__(256) void kA(
    const float* __restrict__ gu, const float* __restrict__ nets,
    const int* __restrict__ net_index, unsigned* __restrict__ keys,
    unsigned* __restrict__ hist0)
{
    const int blk = blockIdx.x;
    const int b = blk / NTILES;
    int ti, tj; tile_decode(blk % NTILES, ti, tj);
    const int i0 = ti * 32, j0 = tj * 32;
    const float* ub = gu + (size_t)b * NN;
    const float* lb = nets + (size_t)net_index[b] * NN;

    __shared__ float Hij[32][33];
    __shared__ float Hji[32][33];
    __shared__ unsigned hist[256];
    hist[threadIdx.x] = 0;

    const int r = threadIdx.x >> 5;
    const int c = threadIdx.x & 31;

    #pragma unroll
    for (int s = 0; s < 4; ++s) {
        int rr = r + 8 * s;
        int i = i0 + rr, j = j0 + c;
        if (i < N_SZ && j < N_SZ) {
            float u = ub[i * N_SZ + j];
            u = fminf(fmaxf(u, 1e-10f), 1.0f - 1e-10f);
            Hij[rr][c] = lb[i * N_SZ + j] - logf(-logf(u));
        }
        if (ti != tj) {
            int i2 = j0 + rr, j2 = i0 + c;
            if (i2 < N_SZ && j2 < N_SZ) {
                float u = ub[i2 * N_SZ + j2];
                u = fminf(fmaxf(u, 1e-10f), 1.0f - 1e-10f);
                Hji[rr][c] = lb[i2 * N_SZ + j2] - logf(-logf(u));
            }
        }
    }
    __syncthreads();

    unsigned* kb = keys + (size_t)b * KSTRIDE;
    #pragma unroll
    for (int s = 0; s < 4; ++s) {
        int rr = r + 8 * s;
        int i = i0 + rr, j = j0 + c;
        if (i < N_SZ && j < N_SZ && i <= j) {
            float hji = (ti == tj) ? Hij[c][rr] : Hji[c][rr];
            float sv = 0.5f * (Hij[rr][c] + hji);
            unsigned key = sortkey(sv);
            int base = i * N_SZ - (i * (i - 1)) / 2;
            kb[base + (j - i)] = key;
            atomicAdd(&hist[key >> 24], 1u);
        }
    }
    __syncthreads();
    if (hist[threadIdx.x]) atomicAdd(&hist0[b * 256 + threadIdx.x], hist[threadIdx.x]);
}

// -------- kSel: pick bucket for this round, update (prefix, kk) -------------
__global__ __launch_bounds__(256) void kSel(
    const unsigned* __restrict__ histr, unsigned* __restrict__ sel, int round)
{
    const int b = blockIdx.x;
    __shared__ unsigned h[256];
    h[threadIdx.x] = histr[b * 256 + threadIdx.x];
    __syncthreads();
    if (threadIdx.x == 0) {
        int kk = (round == 0) ? KSEL : (int)sel[b * 2 + 1];
        unsigned prefix = (round == 0) ? 0u : sel[b * 2];
        int cum = 0; int bsel = 0;
        for (int bn = 255; bn >= 0; --bn) {
            int cc = (int)h[bn];
            if (cum + cc >= kk) { bsel = bn; kk = kk - cum; break; }
            cum += cc;
        }
        sel[b * 2] = (prefix << 8) | (unsigned)bsel;
        sel[b * 2 + 1] = (unsigned)kk;
    }
}

// -------- kScan: histogram next byte among keys matching current prefix -----
__global__ __launch_bounds__(256) void kScan(
    const unsigned* __restrict__ keys, const unsigned* __restrict__ sel,
    unsigned* __restrict__ histr, int shift)
{
    const int blk = blockIdx.x;
    const int b = blk / SCAN_CH;
    const int ch = blk % SCAN_CH;
    const unsigned prefix = sel[b * 2];
    __shared__ unsigned hist[256];
    hist[threadIdx.x] = 0;
    __syncthreads();
    const unsigned* kb = keys + (size_t)b * KSTRIDE;
    const int per = (NUPPER + SCAN_CH - 1) / SCAN_CH;
    const int lo = ch * per;
    const int hi = (lo + per < NUPPER) ? lo + per : NUPPER;
    for (int idx = lo + threadIdx.x; idx < hi; idx += 256) {
        unsigned key = kb[idx];
        if ((key >> (shift + 8)) == prefix)
            atomicAdd(&hist[(key >> shift) & 255u], 1u);
    }
    __syncthreads();
    if (hist[threadIdx.x]) atomicAdd(&histr[b * 256 + threadIdx.x], hist[threadIdx.x]);
}

// -------- kW: write 0/1 adj (fp32 + bf16 K-padded), collect exact ties ------
__global__ __launch_bounds__(256) void kW(
    const unsigned* __restrict__ keys, const unsigned* __restrict__ sel,
    unsigned* __restrict__ candCnt, unsigned* __restrict__ cand,
    float* __restrict__ out_base, ushort_t* __restrict__ adjb16)
{
    const int blk = blockIdx.x;
    const int b = blk / NTILES;
    int ti, tj; tile_decode(blk % NTILES, ti, tj);
    const int i0 = ti * 32, j0 = tj * 32;
    const unsigned kth = sel[b * 2];
    const unsigned* kb = keys + (size_t)b * KSTRIDE;
    float* adj = out_base + ADJ_OFF + (size_t)b * NN;
    ushort_t* ab = adjb16 + (size_t)b * (N_SZ * ADJ_STRIDE);

    __shared__ float V[32][33];
    const int r = threadIdx.x >> 5;
    const int c = threadIdx.x & 31;

    #pragma unroll
    for (int s = 0; s < 4; ++s) {
        int rr = r + 8 * s;
        int i = i0 + rr, j = j0 + c;
        if (i < N_SZ && j < N_SZ && i <= j) {
            int base = i * N_SZ - (i * (i - 1)) / 2;
            unsigned key = kb[base + (j - i)];
            float v = (key > kth) ? 1.0f : 0.0f;
            if (key == kth) {
                unsigned p = atomicAdd(&candCnt[b], 1u);
                if (p < CAND_CAP) cand[(size_t)b * CAND_CAP + p] = (unsigned)(i * N_SZ + j);
            }
            V[rr][c] = v;
            if (ti == tj) V[c][rr] = v;
        }
    }
    __syncthreads();
    #pragma unroll
    for (int s = 0; s < 4; ++s) {
        int rr = r + 8 * s;
        int i = i0 + rr, j = j0 + c;
        if (i < N_SZ) {
            float v = (j < N_SZ) ? V[rr][c] : 0.0f;
            if (j < N_SZ) adj[i * N_SZ + j] = v;
            ab[i * ADJ_STRIDE + j] = (v != 0.0f) ? (ushort_t)0x3F80 : (ushort_t)0;
        }
    }
    if (ti != tj) {
        #pragma unroll
        for (int s = 0; s < 4; ++s) {
            int rr = r + 8 * s;
            int i2 = j0 + rr, j2 = i0 + c;
            if (i2 < N_SZ) {
                float v = V[c][rr];
                adj[i2 * N_SZ + j2] = v;
                ab[i2 * ADJ_STRIDE + j2] = (v != 0.0f) ? (ushort_t)0x3F80 : (ushort_t)0;
            }
        }
    }
}

// -------- kT: deterministically include first-kk ties by flat index ---------
__global__ void kT(const unsigned* __restrict__ sel,
                   const unsigned* __restrict__ candCnt,
                   const unsigned* __restrict__ cand,
                   float* __restrict__ out_base, ushort_t* __restrict__ adjb16)
{
    const int b = blockIdx.x;
    if (threadIdx.x != 0) return;
    int kk = (int)sel[b * 2 + 1];
    int cnt = (int)candCnt[b];
    if (cnt > CAND_CAP) cnt = CAND_CAP;
    float* adj = out_base + ADJ_OFF + (size_t)b * NN;
    ushort_t* ab = adjb16 + (size_t)b * (N_SZ * ADJ_STRIDE);
    int take = kk < cnt ? kk : cnt;
    unsigned used[64];
    int nu = 0;
    for (int t = 0; t < take; ++t) {
        unsigned best = 0xFFFFFFFFu;
        for (int q = 0; q < cnt; ++q) {
            unsigned v = cand[(size_t)b * CAND_CAP + q];
            bool skip = false;
            for (int u = 0; u < nu; ++u) if (used[u] == v) { skip = true; break; }
            if (!skip && v < best) best = v;
        }
        if (best == 0xFFFFFFFFu) break;
        if (nu < 64) used[nu++] = best;
        int i = (int)(best / N_SZ), j = (int)(best % N_SZ);
        adj[i * N_SZ + j] = 1.0f;
        adj[j * N_SZ + i] = 1.0f;
        ab[i * ADJ_STRIDE + j] = (ushort_t)0x3F80;
        ab[j * ADJ_STRIDE + i] = (ushort_t)0x3F80;
    }
}

// -------- kWprep: w_gnn fp32 -> bf16 kgroup layout, padded to 28 kgroups ----
// wkg elem off = kg*2048 + n*8 + ki, value = w[(kg*8+ki)*256 + n] (0 if k>=200)
__global__ __launch_bounds__(256) void kWprep(
    const float* __restrict__ wg, ushort_t* __restrict__ wkg)
{
    int e = blockIdx.x * 256 + threadIdx.x;   // 224 blocks * 256 = 57344
    int kg = e >> 11;
    int rem = e & 2047;
    int n = rem >> 3;
    int ki = rem & 7;
    int k = kg * 8 + ki;
    wkg[e] = (k < FIN) ? f2b(wg[k * OUT_F + n]) : (ushort_t)0;
}

// -------- K2: XW = x @ w_gnn via bf16 MFMA -> XWM kgroup layout -------------
// 800 blocks x 64 rows; 4 waves = 64-col quadrants; K=200 padded to 224
__global__ __launch_bounds__(256) void k2_mfma(
    const float* __restrict__ x, const ushort_t* __restrict__ wkg,
    ushort_t* __restrict__ xwm)
{
    const int r0 = blockIdx.x * 64;
    const int tid = threadIdx.x;
    const int w = tid >> 6;
    const int l = tid & 63;
    const int g = l >> 4;
    const int r = l & 15;

    __shared__ __align__(16) char pool[32768];
    ushort_t* As = (ushort_t*)pool;              // [64 rows][32 k] = 4 KB
    ushort_t* Bs = (ushort_t*)(pool + 4096);     // [4 kgrp][256 n][8 k] = 16 KB
    ushort_t* Cs = (ushort_t*)pool;              // 32 KB after loop

    f32x4 acc[4][4];
    #pragma unroll
    for (int mf = 0; mf < 4; ++mf)
        #pragma unroll
        for (int nf = 0; nf < 4; ++nf)
            acc[mf][nf] = (f32x4){0.f, 0.f, 0.f, 0.f};

    // A-load lambda state: thread loads 2 float4 (rows fidx>>3, f4col fidx&7)
    const int fidx0 = tid * 2;
    const int arow0 = fidx0 >> 3,     af4c0 = fidx0 & 7;
    const int arow1 = (fidx0 + 1) >> 3, af4c1 = (fidx0 + 1) & 7;

    float4 a0, a1;
    int4 bv[4];
    {   // prefetch chunk 0
        a0 = *(const float4*)(x + (size_t)(r0 + arow0) * FIN + af4c0 * 4);
        a1 = *(const float4*)(x + (size_t)(r0 + arow1) * FIN + af4c1 * 4);
        const int4* src = (const int4*)wkg;
        #pragma unroll
        for (int q = 0; q < 4; ++q) bv[q] = src[tid * 4 + q];
    }

    for (int c = 0; c < 7; ++c) {
        __syncthreads();
        *(u16x4*)(As + arow0 * 32 + af4c0 * 4) = f2b4(a0);
        *(u16x4*)(As + arow1 * 32 + af4c1 * 4) = f2b4(a1);
        {
            int4* dst = (int4*)Bs;
            #pragma unroll
            for (int q = 0; q < 4; ++q) dst[tid * 4 + q] = bv[q];
        }
        __syncthreads();

        if (c < 6) {   // prefetch next chunk before MFMA cluster
            int cn = c + 1;
            bool v0 = (cn < 6) || (af4c0 < 2);
            bool v1 = (cn < 6) || (af4c1 < 2);
            a0 = v0 ? *(const float4*)(x + (size_t)(r0 + arow0) * FIN + cn * 32 + af4c0 * 4)
                    : (float4){0.f, 0.f, 0.f, 0.f};
            a1 = v1 ? *(const float4*)(x + (size_t)(r0 + arow1) * FIN + cn * 32 + af4c1 * 4)
                    : (float4){0.f, 0.f, 0.f, 0.f};
            const int4* src = (const int4*)wkg;
            #pragma unroll
            for (int q = 0; q < 4; ++q) bv[q] = src[cn * 1024 + tid * 4 + q];
        }

        bf16x8 af[4], bf[4];
        #pragma unroll
        for (int mf = 0; mf < 4; ++mf)
            af[mf] = *(const bf16x8*)(As + (mf * 16 + r) * 32 + g * 8);
        #pragma unroll
        for (int nf = 0; nf < 4; ++nf)
            bf[nf] = *(const bf16x8*)(Bs + g * 2048 + (w * 64 + nf * 16 + r) * 8);
        #pragma unroll
        for (int mf = 0; mf < 4; ++mf)
            #pragma unroll
            for (int nf = 0; nf < 4; ++nf)
                acc[mf][nf] = __builtin_amdgcn_mfma_f32_16x16x32_bf16(
                    af[mf], bf[nf], acc[mf][nf], 0, 0, 0);
    }

    __syncthreads();   // all frag reads done before Cs aliases As/Bs
    // scatter to Cs in kgroup layout (rows local 0..63)
    #pragma unroll
    for (int mf = 0; mf < 4; ++mf) {
        #pragma unroll
        for (int jj = 0; jj < 4; ++jj) {
            int row = mf * 16 + g * 4 + jj;
            #pragma unroll
            for (int nf = 0; nf < 4; ++nf) {
                int col = w * 64 + nf * 16 + r;
                Cs[((row >> 3) << 11) + col * 8 + (row & 7)] = f2b(acc[mf][nf][jj]);
            }
        }
    }
    __syncthreads();
    // linear write-out: 8 local kgroups (8-row groups never cross batch bound)
    #pragma unroll
    for (int kg = 0; kg < 8; ++kg) {
        int grow0 = r0 + kg * 8;
        int bb = grow0 / N_SZ;
        int jb = grow0 % N_SZ;
        ushort_t* dst = xwm + (size_t)bb * XWM_PB + ((jb >> 3) << 11);
        *(int4*)(dst + tid * 8) = *(const int4*)(Cs + (kg << 11) + tid * 8);
    }
}

// -------- K3: emb = relu(adj @ XW) via bf16 MFMA ----------------------------
__global__ __launch_bounds__(256) void k3_mfma(
    const ushort_t* __restrict__ adjb16, const ushort_t* __restrict__ xwm,
    float* __restrict__ out_base)
{
    const int blk = blockIdx.x;
    const int b = blk >> 2;
    const int mt = blk & 3;
    const int tid = threadIdx.x;
    const int w = tid >> 6;
    const int l = tid & 63;
    const int g = l >> 4;
    const int r = l & 15;

    __shared__ ushort_t As[64 * 32];
    __shared__ ushort_t Bs[4 * 2048];

    const ushort_t* adjb = adjb16 + (size_t)b * (N_SZ * ADJ_STRIDE);
    const ushort_t* xwb = xwm + (size_t)b * XWM_PB;

    f32x4 acc[4][4];
    #pragma unroll
    for (int mf = 0; mf < 4; ++mf)
        #pragma unroll
        for (int nf = 0; nf < 4; ++nf)
            acc[mf][nf] = (f32x4){0.f, 0.f, 0.f, 0.f};

    const int arow = tid >> 2;
    int grow = mt * 64 + arow;
    if (grow > N_SZ - 1) grow = N_SZ - 1;
    const ushort_t* agp = adjb + grow * ADJ_STRIDE + (tid & 3) * 8;

    for (int c = 0; c < 7; ++c) {
        int4 av = *(const int4*)(agp + c * 32);
        int4 bv0 = *(const int4*)(xwb + c * 8192 + (0 * 256 + tid) * 8);
        int4 bv1 = *(const int4*)(xwb + c * 8192 + (1 * 256 + tid) * 8);
        int4 bv2 = *(const int4*)(xwb + c * 8192 + (2 * 256 + tid) * 8);
        int4 bv3 = *(const int4*)(xwb + c * 8192 + (3 * 256 + tid) * 8);
        __syncthreads();
        *(int4*)(As + tid * 8) = av;
        *(int4*)(Bs + (0 * 256 + tid) * 8) = bv0;
        *(int4*)(Bs + (1 * 256 + tid) * 8) = bv1;
        *(int4*)(Bs + (2 * 256 + tid) * 8) = bv2;
        *(int4*)(Bs + (3 * 256 + tid) * 8) = bv3;
        __syncthreads();

        bf16x8 af[4], bf[4];
        #pragma unroll
        for (int mf = 0; mf < 4; ++mf)
            af[mf] = *(const bf16x8*)(As + (mf * 16 + r) * 32 + g * 8);
        #pragma unroll
        for (int nf = 0; nf < 4; ++nf)
            bf[nf] = *(const bf16x8*)(Bs + g * 2048 + (w * 64 + nf * 16 + r) * 8);
        #pragma unroll
        for (int mf = 0; mf < 4; ++mf)
            #pragma unroll
            for (int nf = 0; nf < 4; ++nf)
                acc[mf][nf] = __builtin_amdgcn_mfma_f32_16x16x32_bf16(
                    af[mf], bf[nf], acc[mf][nf], 0, 0, 0);
    }

    #pragma unroll
    for (int mf = 0; mf < 4; ++mf) {
        #pragma unroll
        for (int j = 0; j < 4; ++j) {
            int rowl = mf * 16 + g * 4 + j;
            int grow2 = mt * 64 + rowl;
            if (grow2 < N_SZ) {
                size_t rbase = EMB_OFF + ((size_t)b * N_SZ + grow2) * OUT_F;
                #pragma unroll
                for (int nf = 0; nf < 4; ++nf) {
                    int col = w * 64 + nf * 16 + r;
                    out_base[rbase + col] = fmaxf(acc[mf][nf][j], 0.0f);
                }
            }
        }
    }
}

// -------- K4: out = emb @ w_lin + b  (1 row per wave, 4 rows per block) -----
__global__ __launch_bounds__(256) void k4_out(
    const float* __restrict__ wl, const float* __restrict__ bl,
    float* __restrict__ out_base)
{
    const int wave = threadIdx.x >> 6;
    const int lane = threadIdx.x & 63;
    const int row = blockIdx.x * 4 + wave;    // 12800 blocks

    float4 e = *(const float4*)(out_base + EMB_OFF + (size_t)row * OUT_F + lane * 4);
    const float* wp = wl + (size_t)lane * 4 * NCLS;
    float pr[NCLS];
    #pragma unroll
    for (int c = 0; c < NCLS; ++c)
        pr[c] = e.x * wp[c] + e.y * wp[NCLS + c] + e.z * wp[2 * NCLS + c] + e.w * wp[3 * NCLS + c];
    #pragma unroll
    for (int c = 0; c < NCLS; ++c) {
        #pragma unroll
        for (int off = 32; off >= 1; off >>= 1)
            pr[c] += __shfl_xor(pr[c], off, 64);
    }
    if (lane == 0) {
        float4 o0 = {pr[0] + bl[0], pr[1] + bl[1], pr[2] + bl[2], pr[3] + bl[3]};
        float4 o1 = {pr[4] + bl[4], pr[5] + bl[5], pr[6] + bl[6], pr[7] + bl[7]};
        *(float4*)(out_base + (size_t)row * NCLS) = o0;
        *(float4*)(out_base + (size_t)row * NCLS + 4) = o1;
    }
}

extern "C" void kernel_launch(void* const* d_in, const int* in_sizes, int n_in,
                              void* d_out, int out_size, void* d_ws, size_t ws_size,
                              hipStream_t stream) {
    const float* x    = (const float*)d_in[0];
    const float* gu   = (const float*)d_in[1];
    const float* nets = (const float*)d_in[2];
    const float* wg   = (const float*)d_in[3];
    const float* wl   = (const float*)d_in[4];
    const float* bl   = (const float*)d_in[5];
    const int*   nidx = (const int*)d_in[6];
    float* out = (float*)d_out;

    char* ws = (char*)d_ws;
    unsigned* keys    = (unsigned*)(ws + KEYS_OFF_B);
    unsigned* hist    = (unsigned*)(ws + HIST_OFF_B);
    unsigned* sel     = (unsigned*)(ws + SEL_OFF_B);
    unsigned* candCnt = (unsigned*)(ws + CCNT_OFF_B);
    unsigned* cand    = (unsigned*)(ws + CAND_OFF_B);
    ushort_t* xwm     = (ushort_t*)(ws + KEYS_OFF_B);   // aliases keys; k2 after kT
    ushort_t* wkg     = (ushort_t*)(ws + WKG_OFF_B);
    ushort_t* adjb16  = (ushort_t*)(ws + ADJB16_OFF_B);

    hipMemsetAsync(ws + HIST_OFF_B, 0, MEMSET_LEN, stream);

    kWprep<<<224, 256, 0, stream>>>(wg, wkg);
    kA<<<B_SZ * NTILES, 256, 0, stream>>>(gu, nets, nidx, keys, hist);
    kSel<<<B_SZ, 256, 0, stream>>>(hist, sel, 0);
    kScan<<<B_SZ * SCAN_CH, 256, 0, stream>>>(keys, sel, hist + 256 * B_SZ, 16);
    kSel<<<B_SZ, 256, 0, stream>>>(hist + 256 * B_SZ, sel, 1);
    kScan<<<B_SZ * SCAN_CH, 256, 0, stream>>>(keys, sel, hist + 2 * 256 * B_SZ, 8);
    kSel<<<B_SZ, 256, 0, stream>>>(hist + 2 * 256 * B_SZ, sel, 2);
    kScan<<<B_SZ * SCAN_CH, 256, 0, stream>>>(keys, sel, hist + 3 * 256 * B_SZ, 0);
    kSel<<<B_SZ, 256, 0, stream>>>(hist + 3 * 256 * B_SZ, sel, 3);
    kW<<<B_SZ * NTILES, 256, 0, stream>>>(keys, sel, candCnt, cand, out, adjb16);
    kT<<<B_SZ, 64, 0, stream>>>(sel, candCnt, cand, out, adjb16);

    k2_mfma<<<(B_SZ * N_SZ) / 64, 256, 0, stream>>>(x, wkg, xwm);
    k3_mfma<<<B_SZ * 4, 256, 0, stream>>>(adjb16, xwm, out);
    k4_out<<<(B_SZ * N_SZ) / 4, 256, 0, stream>>>(wl, bl, out);
}

// Round 6
// 216.182 us; speedup vs baseline: 2.7244x; 1.1544x over previous
//
#include <hip/hip_runtime.h>
#include <math.h>

#define B_SZ 256
#define N_SZ 200
#define NN (N_SZ * N_SZ)          // 40000
#define FIN 200
#define OUT_F 256
#define NCLS 8
#define KSEL 3980
#define NUPPER 20100              // N*(N+1)/2
#define KSTRIDE 20128
#define NT 7                      // ceil(200/32) tiles per dim
#define NTILES 28                 // NT*(NT+1)/2 upper tile pairs
#define SCAN_CH 16
#define CAND_CAP 2048

#define ADJ_STRIDE 224            // adj_bf16 row stride (K-padded, zeros beyond 199)
#define KGRP_PB 25                // kgroups per batch (200/8)
#define XWM_PB (KGRP_PB * 2048)   // 51200 elems per batch in mfma layout

#define EMB_OFF (B_SZ * N_SZ * NCLS)               // 409600
#define ADJ_OFF (EMB_OFF + B_SZ * N_SZ * OUT_F)    // 13516800

// ---- ws layout (bytes) ----
// keys:     [0, 20,611,072)            dead after kW -- aliased by XW_mfma
// hist/sel/cand: [20.6M, 23.76M)       dead after kT
// XW_mfma:  [0, 26,214,400)            written by k2 (after kT), read by k3
// w_kgrp:   [26,214,400, +114,688)     bf16 w kgroup layout, 28 kgrp (3 zero)
// adj_bf16: [26,329,088, +22,937,600)  end 49,266,688 (< 52.4 MB proven)
#define KEYS_OFF_B   0
#define HIST_OFF_B   20611072
#define SEL_OFF_B    21659648
#define CCNT_OFF_B   21661696
#define CAND_OFF_B   21662720
#define WKG_OFF_B    26214400
#define ADJB16_OFF_B 26329088
#define MEMSET_LEN   (1048576 + 2048 + 1024)

typedef unsigned short ushort_t;
typedef float f32x4 __attribute__((ext_vector_type(4)));
typedef short bf16x8 __attribute__((ext_vector_type(8)));
typedef ushort_t u16x4 __attribute__((ext_vector_type(4)));

__device__ __forceinline__ unsigned sortkey(float f) {
    unsigned u = __float_as_uint(f);
    return (u & 0x80000000u) ? ~u : (u | 0x80000000u);
}

__device__ __forceinline__ ushort_t f2b(float f) {   // RNE fp32->bf16
    unsigned u = __float_as_uint(f);
    return (ushort_t)((u + 0x7FFFu + ((u >> 16) & 1u)) >> 16);
}

__device__ __forceinline__ bf16x8 f2b8(float4 lo, float4 hi) {
    bf16x8 r;
    r[0] = (short)f2b(lo.x); r[1] = (short)f2b(lo.y);
    r[2] = (short)f2b(lo.z); r[3] = (short)f2b(lo.w);
    r[4] = (short)f2b(hi.x); r[5] = (short)f2b(hi.y);
    r[6] = (short)f2b(hi.z); r[7] = (short)f2b(hi.w);
    return r;
}

__device__ __forceinline__ void tile_decode(int t, int& ti, int& tj) {
    int a = 0, rem = t;
    while (rem >= NT - a) { rem -= NT - a; ++a; }
    ti = a; tj = a + rem;
}

// -------- kA: compute sym keys (packed upper-tri) + round-0 histogram -------
__global__ __launch_bounds__(256) void kA(
    const float* __restrict__ gu, const float* __restrict__ nets,
    const int* __restrict__ net_index, unsigned* __restrict__ keys,
    unsigned* __restrict__ hist0)
{
    const int blk = blockIdx.x;
    const int b = blk / NTILES;
    int ti, tj; tile_decode(blk % NTILES, ti, tj);
    const int i0 = ti * 32, j0 = tj * 32;
    const float* ub = gu + (size_t)b * NN;
    const float* lb = nets + (size_t)net_index[b] * NN;

    __shared__ float Hij[32][33];
    __shared__ float Hji[32][33];
    __shared__ unsigned hist[256];
    hist[threadIdx.x] = 0;

    const int r = threadIdx.x >> 5;
    const int c = threadIdx.x & 31;

    #pragma unroll
    for (int s = 0; s < 4; ++s) {
        int rr = r + 8 * s;
        int i = i0 + rr, j = j0 + c;
        if (i < N_SZ && j < N_SZ) {
            float u = ub[i * N_SZ + j];
            u = fminf(fmaxf(u, 1e-10f), 1.0f - 1e-10f);
            Hij[rr][c] = lb[i * N_SZ + j] - logf(-logf(u));
        }
        if (ti != tj) {
            int i2 = j0 + rr, j2 = i0 + c;
            if (i2 < N_SZ && j2 < N_SZ) {
                float u = ub[i2 * N_SZ + j2];
                u = fminf(fmaxf(u, 1e-10f), 1.0f - 1e-10f);
                Hji[rr][c] = lb[i2 * N_SZ + j2] - logf(-logf(u));
            }
        }
    }
    __syncthreads();

    unsigned* kb = keys + (size_t)b * KSTRIDE;
    #pragma unroll
    for (int s = 0; s < 4; ++s) {
        int rr = r + 8 * s;
        int i = i0 + rr, j = j0 + c;
        if (i < N_SZ && j < N_SZ && i <= j) {
            float hji = (ti == tj) ? Hij[c][rr] : Hji[c][rr];
            float sv = 0.5f * (Hij[rr][c] + hji);
            unsigned key = sortkey(sv);
            int base = i * N_SZ - (i * (i - 1)) / 2;
            kb[base + (j - i)] = key;
            atomicAdd(&hist[key >> 24], 1u);
        }
    }
    __syncthreads();
    if (hist[threadIdx.x]) atomicAdd(&hist0[b * 256 + threadIdx.x], hist[threadIdx.x]);
}

// -------- kSel: pick bucket for this round, update (prefix, kk) -------------
__global__ __launch_bounds__(256) void kSel(
    const unsigned* __restrict__ histr, unsigned* __restrict__ sel, int round)
{
    const int b = blockIdx.x;
    __shared__ unsigned h[256];
    h[threadIdx.x] = histr[b * 256 + threadIdx.x];
    __syncthreads();
    if (threadIdx.x == 0) {
        int kk = (round == 0) ? KSEL : (int)sel[b * 2 + 1];
        unsigned prefix = (round == 0) ? 0u : sel[b * 2];
        int cum = 0; int bsel = 0;
        for (int bn = 255; bn >= 0; --bn) {
            int cc = (int)h[bn];
            if (cum + cc >= kk) { bsel = bn; kk = kk - cum; break; }
            cum += cc;
        }
        sel[b * 2] = (prefix << 8) | (unsigned)bsel;
        sel[b * 2 + 1] = (unsigned)kk;
    }
}

// -------- kScan: histogram next byte among keys matching current prefix -----
__global__ __launch_bounds__(256) void kScan(
    const unsigned* __restrict__ keys, const unsigned* __restrict__ sel,
    unsigned* __restrict__ histr, int shift)
{
    const int blk = blockIdx.x;
    const int b = blk / SCAN_CH;
    const int ch = blk % SCAN_CH;
    const unsigned prefix = sel[b * 2];
    __shared__ unsigned hist[256];
    hist[threadIdx.x] = 0;
    __syncthreads();
    const unsigned* kb = keys + (size_t)b * KSTRIDE;
    const int per = (NUPPER + SCAN_CH - 1) / SCAN_CH;
    const int lo = ch * per;
    const int hi = (lo + per < NUPPER) ? lo + per : NUPPER;
    for (int idx = lo + threadIdx.x; idx < hi; idx += 256) {
        unsigned key = kb[idx];
        if ((key >> (shift + 8)) == prefix)
            atomicAdd(&hist[(key >> shift) & 255u], 1u);
    }
    __syncthreads();
    if (hist[threadIdx.x]) atomicAdd(&histr[b * 256 + threadIdx.x], hist[threadIdx.x]);
}

// -------- kW: write 0/1 adj (fp32 + bf16 K-padded), collect exact ties ------
__global__ __launch_bounds__(256) void kW(
    const unsigned* __restrict__ keys, const unsigned* __restrict__ sel,
    unsigned* __restrict__ candCnt, unsigned* __restrict__ cand,
    float* __restrict__ out_base, ushort_t* __restrict__ adjb16)
{
    const int blk = blockIdx.x;
    const int b = blk / NTILES;
    int ti, tj; tile_decode(blk % NTILES, ti, tj);
    const int i0 = ti * 32, j0 = tj * 32;
    const unsigned kth = sel[b * 2];
    const unsigned* kb = keys + (size_t)b * KSTRIDE;
    float* adj = out_base + ADJ_OFF + (size_t)b * NN;
    ushort_t* ab = adjb16 + (size_t)b * (N_SZ * ADJ_STRIDE);

    __shared__ float V[32][33];
    const int r = threadIdx.x >> 5;
    const int c = threadIdx.x & 31;

    #pragma unroll
    for (int s = 0; s < 4; ++s) {
        int rr = r + 8 * s;
        int i = i0 + rr, j = j0 + c;
        if (i < N_SZ && j < N_SZ && i <= j) {
            int base = i * N_SZ - (i * (i - 1)) / 2;
            unsigned key = kb[base + (j - i)];
            float v = (key > kth) ? 1.0f : 0.0f;
            if (key == kth) {
                unsigned p = atomicAdd(&candCnt[b], 1u);
                if (p < CAND_CAP) cand[(size_t)b * CAND_CAP + p] = (unsigned)(i * N_SZ + j);
            }
            V[rr][c] = v;
            if (ti == tj) V[c][rr] = v;
        }
    }
    __syncthreads();
    #pragma unroll
    for (int s = 0; s < 4; ++s) {
        int rr = r + 8 * s;
        int i = i0 + rr, j = j0 + c;
        if (i < N_SZ) {
            float v = (j < N_SZ) ? V[rr][c] : 0.0f;
            if (j < N_SZ) adj[i * N_SZ + j] = v;
            ab[i * ADJ_STRIDE + j] = (v != 0.0f) ? (ushort_t)0x3F80 : (ushort_t)0;
        }
    }
    if (ti != tj) {
        #pragma unroll
        for (int s = 0; s < 4; ++s) {
            int rr = r + 8 * s;
            int i2 = j0 + rr, j2 = i0 + c;
            if (i2 < N_SZ) {
                float v = V[c][rr];
                adj[i2 * N_SZ + j2] = v;
                ab[i2 * ADJ_STRIDE + j2] = (v != 0.0f) ? (ushort_t)0x3F80 : (ushort_t)0;
            }
        }
    }
}

// -------- kT: deterministically include first-kk ties by flat index ---------
__global__ void kT(const unsigned* __restrict__ sel,
                   const unsigned* __restrict__ candCnt,
                   const unsigned* __restrict__ cand,
                   float* __restrict__ out_base, ushort_t* __restrict__ adjb16)
{
    const int b = blockIdx.x;
    if (threadIdx.x != 0) return;
    int kk = (int)sel[b * 2 + 1];
    int cnt = (int)candCnt[b];
    if (cnt > CAND_CAP) cnt = CAND_CAP;
    float* adj = out_base + ADJ_OFF + (size_t)b * NN;
    ushort_t* ab = adjb16 + (size_t)b * (N_SZ * ADJ_STRIDE);
    int take = kk < cnt ? kk : cnt;
    unsigned used[64];
    int nu = 0;
    for (int t = 0; t < take; ++t) {
        unsigned best = 0xFFFFFFFFu;
        for (int q = 0; q < cnt; ++q) {
            unsigned v = cand[(size_t)b * CAND_CAP + q];
            bool skip = false;
            for (int u = 0; u < nu; ++u) if (used[u] == v) { skip = true; break; }
            if (!skip && v < best) best = v;
        }
        if (best == 0xFFFFFFFFu) break;
        if (nu < 64) used[nu++] = best;
        int i = (int)(best / N_SZ), j = (int)(best % N_SZ);
        adj[i * N_SZ + j] = 1.0f;
        adj[j * N_SZ + i] = 1.0f;
        ab[i * ADJ_STRIDE + j] = (ushort_t)0x3F80;
        ab[j * ADJ_STRIDE + i] = (ushort_t)0x3F80;
    }
}

// -------- kWprep: w_gnn fp32 -> bf16 kgroup layout, padded to 28 kgroups ----
__global__ __launch_bounds__(256) void kWprep(
    const float* __restrict__ wg, ushort_t* __restrict__ wkg)
{
    int e = blockIdx.x * 256 + threadIdx.x;   // 224 blocks * 256 = 57344
    int kg = e >> 11;
    int rem = e & 2047;
    int n = rem >> 3;
    int ki = rem & 7;
    int k = kg * 8 + ki;
    wkg[e] = (k < FIN) ? f2b(wg[k * OUT_F + n]) : (ushort_t)0;
}

// -------- K2: XW = x @ w_gnn via bf16 MFMA, barrier-free main loop ----------
// A frags: direct from x (fp32->bf16 in reg). B frags: direct from wkg
// (already in fragment layout, L2-hot 114 KB). LDS only for store epilogue.
__global__ __launch_bounds__(256) void k2_mfma(
    const float* __restrict__ x, const ushort_t* __restrict__ wkg,
    ushort_t* __restrict__ xwm)
{
    const int r0 = blockIdx.x * 64;
    const int tid = threadIdx.x;
    const int w = tid >> 6;
    const int l = tid & 63;
    const int g = l >> 4;
    const int r = l & 15;

    __shared__ __align__(16) ushort_t Cs[64 * 256];   // 32 KB epilogue buffer

    f32x4 acc[4][4];
    #pragma unroll
    for (int mf = 0; mf < 4; ++mf)
        #pragma unroll
        for (int nf = 0; nf < 4; ++nf)
            acc[mf][nf] = (f32x4){0.f, 0.f, 0.f, 0.f};

    for (int c = 0; c < 7; ++c) {
        // k offset for A; chunk 6, g>0 covers k>=200: clamp addr (in-bounds,
        // finite garbage) -- B kgroups 25..27 are zero so product vanishes.
        const int koff = (c * 32 + g * 8 < FIN) ? (c * 32 + g * 8) : 0;
        bf16x8 af[4], bf[4];
        #pragma unroll
        for (int mf = 0; mf < 4; ++mf) {
            const float* ap = x + (size_t)(r0 + mf * 16 + r) * FIN + koff;
            float4 lo = *(const float4*)ap;
            float4 hi = *(const float4*)(ap + 4);
            af[mf] = f2b8(lo, hi);
        }
        #pragma unroll
        for (int nf = 0; nf < 4; ++nf)
            bf[nf] = *(const bf16x8*)(wkg + c * 8192 + g * 2048 + (w * 64 + nf * 16 + r) * 8);
        #pragma unroll
        for (int mf = 0; mf < 4; ++mf)
            #pragma unroll
            for (int nf = 0; nf < 4; ++nf)
                acc[mf][nf] = __builtin_amdgcn_mfma_f32_16x16x32_bf16(
                    af[mf], bf[nf], acc[mf][nf], 0, 0, 0);
    }

    // scatter to Cs in kgroup layout (local rows 0..63)
    #pragma unroll
    for (int mf = 0; mf < 4; ++mf) {
        #pragma unroll
        for (int jj = 0; jj < 4; ++jj) {
            int row = mf * 16 + g * 4 + jj;
            #pragma unroll
            for (int nf = 0; nf < 4; ++nf) {
                int col = w * 64 + nf * 16 + r;
                Cs[((row >> 3) << 11) + col * 8 + (row & 7)] = f2b(acc[mf][nf][jj]);
            }
        }
    }
    __syncthreads();
    // linear write-out: 8 local kgroups (8-row groups never cross batch bound)
    #pragma unroll
    for (int kg = 0; kg < 8; ++kg) {
        int grow0 = r0 + kg * 8;
        int bb = grow0 / N_SZ;
        int jb = grow0 % N_SZ;
        ushort_t* dst = xwm + (size_t)bb * XWM_PB + ((jb >> 3) << 11);
        *(int4*)(dst + tid * 8) = *(const int4*)(Cs + (kg << 11) + tid * 8);
    }
}

// -------- K3: emb = relu(adj @ XW) via bf16 MFMA, zero-LDS zero-barrier -----
// XCD-bijective decode keeps all 4 M-tiles of a batch on one XCD (xwm L2-hot)
__global__ __launch_bounds__(256) void k3_mfma(
    const ushort_t* __restrict__ adjb16, const ushort_t* __restrict__ xwm,
    float* __restrict__ out_base)
{
    const int blk = blockIdx.x;
    const int b = (blk & 7) + 8 * (blk >> 5);
    const int mt = (blk >> 3) & 3;
    const int tid = threadIdx.x;
    const int w = tid >> 6;
    const int l = tid & 63;
    const int g = l >> 4;
    const int r = l & 15;

    const ushort_t* adjb = adjb16 + (size_t)b * (N_SZ * ADJ_STRIDE);
    const ushort_t* xwb = xwm + (size_t)b * XWM_PB;

    f32x4 acc[4][4];
    #pragma unroll
    for (int mf = 0; mf < 4; ++mf)
        #pragma unroll
        for (int nf = 0; nf < 4; ++nf)
            acc[mf][nf] = (f32x4){0.f, 0.f, 0.f, 0.f};

    // A row addresses (clamped: rows >=200 computed, discarded at store)
    int arows[4];
    #pragma unroll
    for (int mf = 0; mf < 4; ++mf) {
        int row = mt * 64 + mf * 16 + r;
        arows[mf] = (row < N_SZ) ? row : (N_SZ - 1);
    }

    for (int c = 0; c < 7; ++c) {
        bf16x8 af[4], bf[4];
        #pragma unroll
        for (int mf = 0; mf < 4; ++mf)
            af[mf] = *(const bf16x8*)(adjb + arows[mf] * ADJ_STRIDE + c * 32 + g * 8);
        // chunk 6, g>0 reads kgroups 25..27 (next batch / wkg: finite);
        // A is zero there (adjb16 K-padding) so product vanishes.
        #pragma unroll
        for (int nf = 0; nf < 4; ++nf)
            bf[nf] = *(const bf16x8*)(xwb + c * 8192 + g * 2048 + (w * 64 + nf * 16 + r) * 8);
        #pragma unroll
        for (int mf = 0; mf < 4; ++mf)
            #pragma unroll
            for (int nf = 0; nf < 4; ++nf)
                acc[mf][nf] = __builtin_amdgcn_mfma_f32_16x16x32_bf16(
                    af[mf], bf[nf], acc[mf][nf], 0, 0, 0);
    }

    #pragma unroll
    for (int mf = 0; mf < 4; ++mf) {
        #pragma unroll
        for (int j = 0; j < 4; ++j) {
            int rowl = mf * 16 + g * 4 + j;
            int grow2 = mt * 64 + rowl;
            if (grow2 < N_SZ) {
                size_t rbase = EMB_OFF + ((size_t)b * N_SZ + grow2) * OUT_F;
                #pragma unroll
                for (int nf = 0; nf < 4; ++nf) {
                    int col = w * 64 + nf * 16 + r;
                    out_base[rbase + col] = fmaxf(acc[mf][nf][j], 0.0f);
                }
            }
        }
    }
}

// -------- K4: out = emb @ w_lin + b  (1 row per wave, 4 rows per block) -----
__global__ __launch_bounds__(256) void k4_out(
    const float* __restrict__ wl, const float* __restrict__ bl,
    float* __restrict__ out_base)
{
    const int wave = threadIdx.x >> 6;
    const int lane = threadIdx.x & 63;
    const int row = blockIdx.x * 4 + wave;    // 12800 blocks

    float4 e = *(const float4*)(out_base + EMB_OFF + (size_t)row * OUT_F + lane * 4);
    const float* wp = wl + (size_t)lane * 4 * NCLS;
    float pr[NCLS];
    #pragma unroll
    for (int c = 0; c < NCLS; ++c)
        pr[c] = e.x * wp[c] + e.y * wp[NCLS + c] + e.z * wp[2 * NCLS + c] + e.w * wp[3 * NCLS + c];
    #pragma unroll
    for (int c = 0; c < NCLS; ++c) {
        #pragma unroll
        for (int off = 32; off >= 1; off >>= 1)
            pr[c] += __shfl_xor(pr[c], off, 64);
    }
    if (lane == 0) {
        float4 o0 = {pr[0] + bl[0], pr[1] + bl[1], pr[2] + bl[2], pr[3] + bl[3]};
        float4 o1 = {pr[4] + bl[4], pr[5] + bl[5], pr[6] + bl[6], pr[7] + bl[7]};
        *(float4*)(out_base + (size_t)row * NCLS) = o0;
        *(float4*)(out_base + (size_t)row * NCLS + 4) = o1;
    }
}

extern "C" void kernel_launch(void* const* d_in, const int* in_sizes, int n_in,
                              void* d_out, int out_size, void* d_ws, size_t ws_size,
                              hipStream_t stream) {
    const float* x    = (const float*)d_in[0];
    const float* gu   = (const float*)d_in[1];
    const float* nets = (const float*)d_in[2];
    const float* wg   = (const float*)d_in[3];
    const float* wl   = (const float*)d_in[4];
    const float* bl   = (const float*)d_in[5];
    const int*   nidx = (const int*)d_in[6];
    float* out = (float*)d_out;

    char* ws = (char*)d_ws;
    unsigned* keys    = (unsigned*)(ws + KEYS_OFF_B);
    unsigned* hist    = (unsigned*)(ws + HIST_OFF_B);
    unsigned* sel     = (unsigned*)(ws + SEL_OFF_B);
    unsigned* candCnt = (unsigned*)(ws + CCNT_OFF_B);
    unsigned* cand    = (unsigned*)(ws + CAND_OFF_B);
    ushort_t* xwm     = (ushort_t*)(ws + KEYS_OFF_B);   // aliases keys; k2 after kT
    ushort_t* wkg     = (ushort_t*)(ws + WKG_OFF_B);
    ushort_t* adjb16  = (ushort_t*)(ws + ADJB16_OFF_B);

    hipMemsetAsync(ws + HIST_OFF_B, 0, MEMSET_LEN, stream);

    kWprep<<<224, 256, 0, stream>>>(wg, wkg);
    kA<<<B_SZ * NTILES, 256, 0, stream>>>(gu, nets, nidx, keys, hist);
    kSel<<<B_SZ, 256, 0, stream>>>(hist, sel, 0);
    kScan<<<B_SZ * SCAN_CH, 256, 0, stream>>>(keys, sel, hist + 256 * B_SZ, 16);
    kSel<<<B_SZ, 256, 0, stream>>>(hist + 256 * B_SZ, sel, 1);
    kScan<<<B_SZ * SCAN_CH, 256, 0, stream>>>(keys, sel, hist + 2 * 256 * B_SZ, 8);
    kSel<<<B_SZ, 256, 0, stream>>>(hist + 2 * 256 * B_SZ, sel, 2);
    kScan<<<B_SZ * SCAN_CH, 256, 0, stream>>>(keys, sel, hist + 3 * 256 * B_SZ, 0);
    kSel<<<B_SZ, 256, 0, stream>>>(hist + 3 * 256 * B_SZ, sel, 3);
    kW<<<B_SZ * NTILES, 256, 0, stream>>>(keys, sel, candCnt, cand, out, adjb16);
    kT<<<B_SZ, 64, 0, stream>>>(sel, candCnt, cand, out, adjb16);

    k2_mfma<<<(B_SZ * N_SZ) / 64, 256, 0, stream>>>(x, wkg, xwm);
    k3_mfma<<<B_SZ * 4, 256, 0, stream>>>(adjb16, xwm, out);
    k4_out<<<(B_SZ * N_SZ) / 4, 256, 0, stream>>>(wl, bl, out);
}

// Round 7
// 197.685 us; speedup vs baseline: 2.9793x; 1.0936x over previous
//
#include <hip/hip_runtime.h>
#include <math.h>

#define B_SZ 256
#define N_SZ 200
#define NN (N_SZ * N_SZ)          // 40000
#define FIN 200
#define OUT_F 256
#define NCLS 8
#define KSEL 3980
#define NUPPER 20100              // N*(N+1)/2
#define KSTRIDE 20128
#define NT 7                      // ceil(200/32) tiles per dim
#define NTILES 28                 // NT*(NT+1)/2 upper tile pairs
#define CAND_CAP 2048

#define KGRP_PB 25                // kgroups per batch (200/8)
#define XWM_PB (KGRP_PB * 2048)   // 51200 elems per batch in mfma layout

#define EMB_OFF (B_SZ * N_SZ * NCLS)               // 409600
#define ADJ_OFF (EMB_OFF + B_SZ * N_SZ * OUT_F)    // 13516800

// ---- ws layout (bytes) ----
// keys:    [0, 20,611,072)       written kA, read kFinal/kW; dead after kW
// sel:     [21,659,648, +2048)   written kFinal; read kW/kT   (inside XWM区,
// candCnt: [21,661,696, +1024)    but k2 writes xwm only AFTER kT -- safe)
// cand:    [21,662,720, +2,097,152)
// XW_mfma: [0, 26,214,400)       aliases keys; written k2 (after kT), read k3
// w_kgrp:  [26,214,400, +114,688) bf16 w kgroup layout, 28 kgrp (3 zero)
#define KEYS_OFF_B   0
#define SEL_OFF_B    21659648
#define CCNT_OFF_B   21661696
#define CAND_OFF_B   21662720
#define WKG_OFF_B    26214400

typedef unsigned short ushort_t;
typedef float f32x4 __attribute__((ext_vector_type(4)));
typedef short bf16x8 __attribute__((ext_vector_type(8)));

__device__ __forceinline__ unsigned sortkey(float f) {
    unsigned u = __float_as_uint(f);
    return (u & 0x80000000u) ? ~u : (u | 0x80000000u);
}

__device__ __forceinline__ ushort_t f2b(float f) {   // RNE fp32->bf16
    unsigned u = __float_as_uint(f);
    return (ushort_t)((u + 0x7FFFu + ((u >> 16) & 1u)) >> 16);
}

__device__ __forceinline__ bf16x8 f2b8(float4 lo, float4 hi) {
    bf16x8 r;
    r[0] = (short)f2b(lo.x); r[1] = (short)f2b(lo.y);
    r[2] = (short)f2b(lo.z); r[3] = (short)f2b(lo.w);
    r[4] = (short)f2b(hi.x); r[5] = (short)f2b(hi.y);
    r[6] = (short)f2b(hi.z); r[7] = (short)f2b(hi.w);
    return r;
}

__device__ __forceinline__ void tile_decode(int t, int& ti, int& tj) {
    int a = 0, rem = t;
    while (rem >= NT - a) { rem -= NT - a; ++a; }
    ti = a; tj = a + rem;
}

// -------- kA: compute sym keys (packed upper-tri) ---------------------------
__global__ __launch_bounds__(256) void kA(
    const float* __restrict__ gu, const float* __restrict__ nets,
    const int* __restrict__ net_index, unsigned* __restrict__ keys)
{
    const int blk = blockIdx.x;
    const int b = blk / NTILES;
    int ti, tj; tile_decode(blk % NTILES, ti, tj);
    const int i0 = ti * 32, j0 = tj * 32;
    const float* ub = gu + (size_t)b * NN;
    const float* lb = nets + (size_t)net_index[b] * NN;

    __shared__ float Hij[32][33];
    __shared__ float Hji[32][33];

    const int r = threadIdx.x >> 5;
    const int c = threadIdx.x & 31;

    #pragma unroll
    for (int s = 0; s < 4; ++s) {
        int rr = r + 8 * s;
        int i = i0 + rr, j = j0 + c;
        if (i < N_SZ && j < N_SZ) {
            float u = ub[i * N_SZ + j];
            u = fminf(fmaxf(u, 1e-10f), 1.0f - 1e-10f);
            Hij[rr][c] = lb[i * N_SZ + j] - logf(-logf(u));
        }
        if (ti != tj) {
            int i2 = j0 + rr, j2 = i0 + c;
            if (i2 < N_SZ && j2 < N_SZ) {
                float u = ub[i2 * N_SZ + j2];
                u = fminf(fmaxf(u, 1e-10f), 1.0f - 1e-10f);
                Hji[rr][c] = lb[i2 * N_SZ + j2] - logf(-logf(u));
            }
        }
    }
    __syncthreads();

    unsigned* kb = keys + (size_t)b * KSTRIDE;
    #pragma unroll
    for (int s = 0; s < 4; ++s) {
        int rr = r + 8 * s;
        int i = i0 + rr, j = j0 + c;
        if (i < N_SZ && j < N_SZ && i <= j) {
            float hji = (ti == tj) ? Hij[c][rr] : Hji[c][rr];
            float sv = 0.5f * (Hij[rr][c] + hji);
            int base = i * N_SZ - (i * (i - 1)) / 2;
            kb[base + (j - i)] = sortkey(sv);
        }
    }
}

// -------- kFinal: full 4-round radix select, keys LDS-resident --------------
__global__ __launch_bounds__(256) void kFinal(
    const unsigned* __restrict__ keys, unsigned* __restrict__ sel)
{
    const int b = blockIdx.x;
    const int tid = threadIdx.x;
    __shared__ unsigned kl[NUPPER];       // 80.4 KB
    __shared__ unsigned hist[256];
    __shared__ unsigned sPrefix;
    __shared__ int sKK;

    const unsigned* kb = keys + (size_t)b * KSTRIDE;
    for (int idx = tid; idx < NUPPER; idx += 256) kl[idx] = kb[idx];

    unsigned prefix = 0;
    int kk = KSEL;
    for (int round = 0; round < 4; ++round) {
        const int shift = 24 - 8 * round;
        hist[tid] = 0;
        __syncthreads();
        for (int idx = tid; idx < NUPPER; idx += 256) {
            unsigned key = kl[idx];
            bool in = (round == 0) || ((key >> (shift + 8)) == prefix);
            if (in) atomicAdd(&hist[(key >> shift) & 255u], 1u);
        }
        __syncthreads();
        if (tid == 0) {
            int cum = 0; int bsel = 0; int nkk = kk;
            for (int bn = 255; bn >= 0; --bn) {
                int cc = (int)hist[bn];
                if (cum + cc >= kk) { bsel = bn; nkk = kk - cum; break; }
                cum += cc;
            }
            sPrefix = (prefix << 8) | (unsigned)bsel;
            sKK = nkk;
        }
        __syncthreads();
        prefix = sPrefix;
        kk = sKK;
        __syncthreads();
    }
    if (tid == 0) {
        sel[b * 2] = prefix;
        sel[b * 2 + 1] = (unsigned)kk;
    }
}

// -------- kW: write full 0/1 adj (both triangles), collect exact ties -------
__global__ __launch_bounds__(256) void kW(
    const unsigned* __restrict__ keys, const unsigned* __restrict__ sel,
    unsigned* __restrict__ candCnt, unsigned* __restrict__ cand,
    float* __restrict__ out_base)
{
    const int blk = blockIdx.x;
    const int b = blk / NTILES;
    int ti, tj; tile_decode(blk % NTILES, ti, tj);
    const int i0 = ti * 32, j0 = tj * 32;
    const unsigned kth = sel[b * 2];
    const unsigned* kb = keys + (size_t)b * KSTRIDE;
    float* adj = out_base + ADJ_OFF + (size_t)b * NN;

    __shared__ float V[32][33];
    const int r = threadIdx.x >> 5;
    const int c = threadIdx.x & 31;

    #pragma unroll
    for (int s = 0; s < 4; ++s) {
        int rr = r + 8 * s;
        int i = i0 + rr, j = j0 + c;
        if (i < N_SZ && j < N_SZ && i <= j) {
            int base = i * N_SZ - (i * (i - 1)) / 2;
            unsigned key = kb[base + (j - i)];
            float v = (key > kth) ? 1.0f : 0.0f;
            if (key == kth) {
                unsigned p = atomicAdd(&candCnt[b], 1u);
                if (p < CAND_CAP) cand[(size_t)b * CAND_CAP + p] = (unsigned)(i * N_SZ + j);
            }
            V[rr][c] = v;
            if (ti == tj) V[c][rr] = v;
        }
    }
    __syncthreads();
    #pragma unroll
    for (int s = 0; s < 4; ++s) {
        int rr = r + 8 * s;
        int i = i0 + rr, j = j0 + c;
        if (i < N_SZ && j < N_SZ) adj[i * N_SZ + j] = V[rr][c];
    }
    if (ti != tj) {
        #pragma unroll
        for (int s = 0; s < 4; ++s) {
            int rr = r + 8 * s;
            int i2 = j0 + rr, j2 = i0 + c;
            if (i2 < N_SZ && j2 < N_SZ) adj[i2 * N_SZ + j2] = V[c][rr];
        }
    }
}

// -------- kT: deterministically include first-kk ties by flat index ---------
__global__ void kT(const unsigned* __restrict__ sel,
                   const unsigned* __restrict__ candCnt,
                   const unsigned* __restrict__ cand,
                   float* __restrict__ out_base)
{
    const int b = blockIdx.x;
    if (threadIdx.x != 0) return;
    int kk = (int)sel[b * 2 + 1];
    int cnt = (int)candCnt[b];
    if (cnt > CAND_CAP) cnt = CAND_CAP;
    float* adj = out_base + ADJ_OFF + (size_t)b * NN;
    int take = kk < cnt ? kk : cnt;
    unsigned used[64];
    int nu = 0;
    for (int t = 0; t < take; ++t) {
        unsigned best = 0xFFFFFFFFu;
        for (int q = 0; q < cnt; ++q) {
            unsigned v = cand[(size_t)b * CAND_CAP + q];
            bool skip = false;
            for (int u = 0; u < nu; ++u) if (used[u] == v) { skip = true; break; }
            if (!skip && v < best) best = v;
        }
        if (best == 0xFFFFFFFFu) break;
        if (nu < 64) used[nu++] = best;
        int i = (int)(best / N_SZ), j = (int)(best % N_SZ);
        adj[i * N_SZ + j] = 1.0f;
        adj[j * N_SZ + i] = 1.0f;
    }
}

// -------- kWprep: w_gnn fp32 -> bf16 kgroup layout, padded to 28 kgroups ----
__global__ __launch_bounds__(256) void kWprep(
    const float* __restrict__ wg, ushort_t* __restrict__ wkg)
{
    int e = blockIdx.x * 256 + threadIdx.x;   // 224 blocks * 256 = 57344
    int kg = e >> 11;
    int rem = e & 2047;
    int n = rem >> 3;
    int ki = rem & 7;
    int k = kg * 8 + ki;
    wkg[e] = (k < FIN) ? f2b(wg[k * OUT_F + n]) : (ushort_t)0;
}

// -------- K2: XW = x @ w_gnn via bf16 MFMA, barrier-free main loop ----------
__global__ __launch_bounds__(256) void k2_mfma(
    const float* __restrict__ x, const ushort_t* __restrict__ wkg,
    ushort_t* __restrict__ xwm)
{
    const int r0 = blockIdx.x * 64;
    const int tid = threadIdx.x;
    const int w = tid >> 6;
    const int l = tid & 63;
    const int g = l >> 4;
    const int r = l & 15;

    __shared__ __align__(16) ushort_t Cs[64 * 256];   // 32 KB epilogue buffer

    f32x4 acc[4][4];
    #pragma unroll
    for (int mf = 0; mf < 4; ++mf)
        #pragma unroll
        for (int nf = 0; nf < 4; ++nf)
            acc[mf][nf] = (f32x4){0.f, 0.f, 0.f, 0.f};

    for (int c = 0; c < 7; ++c) {
        // k>=200 (chunk 6, g>0): clamp addr; B kgroups 25..27 are zero.
        const int koff = (c * 32 + g * 8 < FIN) ? (c * 32 + g * 8) : 0;
        bf16x8 af[4], bf[4];
        #pragma unroll
        for (int mf = 0; mf < 4; ++mf) {
            const float* ap = x + (size_t)(r0 + mf * 16 + r) * FIN + koff;
            float4 lo = *(const float4*)ap;
            float4 hi = *(const float4*)(ap + 4);
            af[mf] = f2b8(lo, hi);
        }
        #pragma unroll
        for (int nf = 0; nf < 4; ++nf)
            bf[nf] = *(const bf16x8*)(wkg + c * 8192 + g * 2048 + (w * 64 + nf * 16 + r) * 8);
        #pragma unroll
        for (int mf = 0; mf < 4; ++mf)
            #pragma unroll
            for (int nf = 0; nf < 4; ++nf)
                acc[mf][nf] = __builtin_amdgcn_mfma_f32_16x16x32_bf16(
                    af[mf], bf[nf], acc[mf][nf], 0, 0, 0);
    }

    // scatter to Cs in kgroup layout (local rows 0..63)
    #pragma unroll
    for (int mf = 0; mf < 4; ++mf) {
        #pragma unroll
        for (int jj = 0; jj < 4; ++jj) {
            int row = mf * 16 + g * 4 + jj;
            #pragma unroll
            for (int nf = 0; nf < 4; ++nf) {
                int col = w * 64 + nf * 16 + r;
                Cs[((row >> 3) << 11) + col * 8 + (row & 7)] = f2b(acc[mf][nf][jj]);
            }
        }
    }
    __syncthreads();
    // linear write-out: 8 local kgroups (8-row groups never cross batch bound)
    #pragma unroll
    for (int kg = 0; kg < 8; ++kg) {
        int grow0 = r0 + kg * 8;
        int bb = grow0 / N_SZ;
        int jb = grow0 % N_SZ;
        ushort_t* dst = xwm + (size_t)bb * XWM_PB + ((jb >> 3) << 11);
        *(int4*)(dst + tid * 8) = *(const int4*)(Cs + (kg << 11) + tid * 8);
    }
}

// -------- K3 fused: emb = relu(adj @ XW) via MFMA; out = emb @ w_lin + b ----
// A direct from fp32 adj (f2b in reg; k-tail frags zeroed). XCD-bijective.
__global__ __launch_bounds__(256) void k3_fused(
    const ushort_t* __restrict__ xwm, const float* __restrict__ wl,
    const float* __restrict__ bl, float* __restrict__ out_base)
{
    const int blk = blockIdx.x;
    const int b = (blk & 7) + 8 * (blk >> 5);
    const int mt = (blk >> 3) & 3;
    const int tid = threadIdx.x;
    const int w = tid >> 6;
    const int l = tid & 63;
    const int g = l >> 4;
    const int r = l & 15;

    const float* adjb = out_base + ADJ_OFF + (size_t)b * NN;
    const ushort_t* xwb = xwm + (size_t)b * XWM_PB;

    __shared__ float red[4][4][16][8];   // [w][g][slot][cls] = 8 KB

    f32x4 acc[4][4];
    #pragma unroll
    for (int mf = 0; mf < 4; ++mf)
        #pragma unroll
        for (int nf = 0; nf < 4; ++nf)
            acc[mf][nf] = (f32x4){0.f, 0.f, 0.f, 0.f};

    int arows[4];
    #pragma unroll
    for (int mf = 0; mf < 4; ++mf) {
        int row = mt * 64 + mf * 16 + r;
        arows[mf] = (row < N_SZ) ? row : (N_SZ - 1);
    }

    for (int c = 0; c < 7; ++c) {
        const int col = c * 32 + g * 8;
        const bool areal = (col < FIN);   // false only for c==6, g>0
        bf16x8 af[4], bf[4];
        #pragma unroll
        for (int mf = 0; mf < 4; ++mf) {
            if (areal) {
                const float* ap = adjb + (size_t)arows[mf] * N_SZ + col;
                float4 lo = *(const float4*)ap;
                float4 hi = *(const float4*)(ap + 4);
                af[mf] = f2b8(lo, hi);
            } else {
                af[mf] = (bf16x8){0, 0, 0, 0, 0, 0, 0, 0};  // annihilate k-tail
            }
        }
        // kgroups 25..27 overrun into next batch: A is zero there -> OK
        #pragma unroll
        for (int nf = 0; nf < 4; ++nf)
            bf[nf] = *(const bf16x8*)(xwb + c * 8192 + g * 2048 + (w * 64 + nf * 16 + r) * 8);
        #pragma unroll
        for (int mf = 0; mf < 4; ++mf)
            #pragma unroll
            for (int nf = 0; nf < 4; ++nf)
                acc[mf][nf] = __builtin_amdgcn_mfma_f32_16x16x32_bf16(
                    af[mf], bf[nf], acc[mf][nf], 0, 0, 0);
    }

    // per-lane w_lin rows for its 4 cols
    float wlv[4][NCLS];
    #pragma unroll
    for (int nf = 0; nf < 4; ++nf) {
        int col = w * 64 + nf * 16 + r;
        #pragma unroll
        for (int cls = 0; cls < NCLS; ++cls) wlv[nf][cls] = wl[col * NCLS + cls];
    }

    // emb store + per-slot class partials + r-group reduce
    #pragma unroll
    for (int mf = 0; mf < 4; ++mf) {
        #pragma unroll
        for (int j = 0; j < 4; ++j) {
            int rowl = mf * 16 + g * 4 + j;
            int grow = mt * 64 + rowl;
            float e0 = fmaxf(acc[mf][0][j], 0.0f);
            float e1 = fmaxf(acc[mf][1][j], 0.0f);
            float e2 = fmaxf(acc[mf][2][j], 0.0f);
            float e3 = fmaxf(acc[mf][3][j], 0.0f);
            if (grow < N_SZ) {
                size_t rbase = EMB_OFF + ((size_t)b * N_SZ + grow) * OUT_F;
                out_base[rbase + w * 64 + r]      = e0;
                out_base[rbase + w * 64 + 16 + r] = e1;
                out_base[rbase + w * 64 + 32 + r] = e2;
                out_base[rbase + w * 64 + 48 + r] = e3;
            }
            float pr[NCLS];
            #pragma unroll
            for (int cls = 0; cls < NCLS; ++cls)
                pr[cls] = e0 * wlv[0][cls] + e1 * wlv[1][cls]
                        + e2 * wlv[2][cls] + e3 * wlv[3][cls];
            #pragma unroll
            for (int off = 1; off <= 8; off <<= 1) {
                #pragma unroll
                for (int cls = 0; cls < NCLS; ++cls)
                    pr[cls] += __shfl_xor(pr[cls], off, 64);
            }
            if (r < NCLS) red[w][g][mf * 4 + j][r] = pr[r];
        }
    }
    __syncthreads();

    // final combine over waves: 512 outputs, 2 per thread
    #pragma unroll
    for (int e = tid; e < 64 * NCLS; e += 256) {
        int rowl = e >> 3, cls = e & 7;
        int mf = rowl >> 4, rem = rowl & 15, gg = rem >> 2, jj = rem & 3;
        int slot = mf * 4 + jj;
        int grow = mt * 64 + rowl;
        if (grow < N_SZ) {
            float s = red[0][gg][slot][cls] + red[1][gg][slot][cls]
                    + red[2][gg][slot][cls] + red[3][gg][slot][cls] + bl[cls];
            out_base[((size_t)b * N_SZ + grow) * NCLS + cls] = s;
        }
    }
}

extern "C" void kernel_launch(void* const* d_in, const int* in_sizes, int n_in,
                              void* d_out, int out_size, void* d_ws, size_t ws_size,
                              hipStream_t stream) {
    const float* x    = (const float*)d_in[0];
    const float* gu   = (const float*)d_in[1];
    const float* nets = (const float*)d_in[2];
    const float* wg   = (const float*)d_in[3];
    const float* wl   = (const float*)d_in[4];
    const float* bl   = (const float*)d_in[5];
    const int*   nidx = (const int*)d_in[6];
    float* out = (float*)d_out;

    char* ws = (char*)d_ws;
    unsigned* keys    = (unsigned*)(ws + KEYS_OFF_B);
    unsigned* sel     = (unsigned*)(ws + SEL_OFF_B);
    unsigned* candCnt = (unsigned*)(ws + CCNT_OFF_B);
    unsigned* cand    = (unsigned*)(ws + CAND_OFF_B);
    ushort_t* xwm     = (ushort_t*)(ws + KEYS_OFF_B);   // aliases keys; k2 after kT
    ushort_t* wkg     = (ushort_t*)(ws + WKG_OFF_B);

    hipMemsetAsync(ws + CCNT_OFF_B, 0, 1024, stream);

    kWprep<<<224, 256, 0, stream>>>(wg, wkg);
    kA<<<B_SZ * NTILES, 256, 0, stream>>>(gu, nets, nidx, keys);
    kFinal<<<B_SZ, 256, 0, stream>>>(keys, sel);
    kW<<<B_SZ * NTILES, 256, 0, stream>>>(keys, sel, candCnt, cand, out);
    kT<<<B_SZ, 64, 0, stream>>>(sel, candCnt, cand, out);

    k2_mfma<<<(B_SZ * N_SZ) / 64, 256, 0, stream>>>(x, wkg, xwm);
    k3_fused<<<B_SZ * 4, 256, 0, stream>>>(xwm, wl, bl, out);
}